// Round 2
// baseline (713.464 us; speedup 1.0000x reference)
//
#include <hip/hip_runtime.h>
#include <hip/hip_bf16.h>
#include <cstdint>
#include <cstddef>

// Problem constants
#define NTOK 32768   // P*N*K token-copies
#define FD   256     // input feature dim
#define HD   1024    // hidden dim
#define OD   256     // output dim
#define NEXP 8

// GEMM tiling
#define BM 128
#define BN 128
#define BK 32
#define LDT 40       // LDS row stride (bf16 elems): 32 + 8 pad -> 2-way-max bank aliasing (free)
#define MAX_TILES 272

typedef __bf16 bf16;
typedef __bf16 bf16x8 __attribute__((ext_vector_type(8)));
typedef __bf16 bf16x4 __attribute__((ext_vector_type(4)));
typedef float  f32x4  __attribute__((ext_vector_type(4)));

// ---- workspace layout (bytes) ----
static const size_t O_CNT  = 0;          // int[8]
static const size_t O_CUR  = 64;         // int[8]
static const size_t O_OFF  = 128;        // int[9]
static const size_t O_NT   = 192;        // int[1]
static const size_t O_TE   = 1024;       // int[512] tile -> expert
static const size_t O_TR   = 3072;       // int[512] tile -> row-block within expert
static const size_t O_PERM = 5120;       // int[NTOK] grouped pos -> original token
static const size_t O_XP   = 136192;     // bf16 [NTOK][FD]    (16 MB)
static const size_t O_WG   = 16913408;   // bf16 [E][HD][FD]   (4 MB)
static const size_t O_WU   = 21107712;   // bf16 [E][HD][FD]   (4 MB)
static const size_t O_W1   = 25302016;   // bf16 [E][HD][HD]   (16 MB)
static const size_t O_W2   = 42079232;   // bf16 [E][OD][HD]   (4 MB)
static const size_t O_H    = 46273536;   // bf16 [NTOK][HD]    (64 MB)
static const size_t O_H2   = 113382400;  // bf16 [NTOK][HD]    (64 MB)
// end = 180491264 (~172 MB)

// ---------------- routing ----------------
__global__ void k_hist(const int* __restrict__ sel, int* __restrict__ cnt) {
    int t = blockIdx.x * 256 + threadIdx.x;
    if (t < NTOK) atomicAdd(&cnt[sel[t]], 1);
}

__global__ void k_plan(const int* __restrict__ cnt, int* __restrict__ off,
                       int* __restrict__ tileE, int* __restrict__ tileR,
                       int* __restrict__ nt) {
    if (threadIdx.x == 0 && blockIdx.x == 0) {
        int o = 0;
        for (int e = 0; e < NEXP; e++) { off[e] = o; o += cnt[e]; }
        off[NEXP] = o;
        int n = 0;
        for (int e = 0; e < NEXP; e++) {
            int c = cnt[e];
            int nte = (c + BM - 1) / BM;
            for (int r = 0; r < nte; r++) { tileE[n] = e; tileR[n] = r; n++; }
        }
        *nt = n;
    }
}

__global__ void k_scatter(const int* __restrict__ sel, const int* __restrict__ off,
                          int* __restrict__ cur, int* __restrict__ perm) {
    int t = blockIdx.x * 256 + threadIdx.x;
    if (t < NTOK) {
        int e = sel[t];
        int p = off[e] + atomicAdd(&cur[e], 1);
        perm[p] = t;
    }
}

// gather x rows (fp32) into expert-grouped bf16 Xp
__global__ void k_gather(const float* __restrict__ x, const int* __restrict__ perm,
                         bf16* __restrict__ Xp) {
    int gid = blockIdx.x * 256 + threadIdx.x;   // NTOK*64 threads, 4 floats each
    int pos = gid >> 6;
    int c   = gid & 63;
    int tok = perm[pos];
    float4 v = ((const float4*)x)[(size_t)tok * 64 + c];
    bf16x4 o;
    o.x = (bf16)v.x; o.y = (bf16)v.y; o.z = (bf16)v.z; o.w = (bf16)v.w;
    *(bf16x4*)&Xp[(size_t)pos * FD + c * 4] = o;
}

// W [E][K][N] fp32 -> Wt [E][N][K] bf16 (K-contiguous so B-frags are ds_read_b128-able)
__global__ void k_transpose(const float* __restrict__ W, bf16* __restrict__ Wt,
                            int K, int N) {
    __shared__ float tile[32][33];
    int k0 = blockIdx.x * 32, n0 = blockIdx.y * 32, e = blockIdx.z;
    const float* Ws = W  + (size_t)e * K * N;
    bf16*        Wd = Wt + (size_t)e * K * N;
    int t = threadIdx.x;
    for (int q = 0; q < 4; q++) {
        int idx = t + q * 256; int r = idx >> 5, c = idx & 31;
        tile[r][c] = Ws[(size_t)(k0 + r) * N + n0 + c];
    }
    __syncthreads();
    for (int q = 0; q < 4; q++) {
        int idx = t + q * 256; int n = idx >> 5, k = idx & 31;
        Wd[(size_t)(n0 + n) * K + k0 + k] = (bf16)tile[k][n];
    }
}

// ---------------- GEMM kernels ----------------
// MFMA 16x16x32 bf16 layouts (HW-verified m89/m91/m120):
//   A-frag: lane holds A[m=lane&15][k=(lane>>4)*8 + j], j=0..7
//   B-frag: lane holds B[k=(lane>>4)*8 + j][n=lane&15]
//   C/D   : lane,reg r -> C[(lane>>4)*4 + r][lane&15]

// GEMM1: Hbuf = silu(Xp@Wg + bg) * (Xp@Wu + bu); K=FD=256, N=HD (grid.y=8)
__global__ __launch_bounds__(256) void k_gemm1(
    const bf16* __restrict__ Xp, const bf16* __restrict__ Wgt, const bf16* __restrict__ Wut,
    const float* __restrict__ bg, const float* __restrict__ bu, bf16* __restrict__ Hbuf,
    const int* __restrict__ tileE, const int* __restrict__ tileR,
    const int* __restrict__ off, const int* __restrict__ ntp)
{
    if (blockIdx.x >= *ntp) return;
    __shared__ bf16 As [BM * LDT];
    __shared__ bf16 Bgs[BN * LDT];
    __shared__ bf16 Bus[BN * LDT];
    int e    = tileE[blockIdx.x];
    int row0 = tileR[blockIdx.x] * BM;
    int base = off[e];
    int valid = off[e + 1] - base - row0; if (valid > BM) valid = BM;
    int n0 = blockIdx.y * BN;
    int tid = threadIdx.x;
    int lane = tid & 63, wv = tid >> 6;
    int wm = wv & 1, wn = wv >> 1;
    int lr = lane & 15, qd = lane >> 4;

    f32x4 accg[4][4] = {};
    f32x4 accu[4][4] = {};
    const bf16* Ab  = Xp  + (size_t)(base + row0) * FD;
    const bf16* Bgb = Wgt + ((size_t)e * HD + n0) * FD;
    const bf16* Bub = Wut + ((size_t)e * HD + n0) * FD;

    for (int k0 = 0; k0 < FD; k0 += BK) {
        for (int c = 0; c < 2; c++) {
            int idx = tid + c * 256;
            int m = idx >> 2, ko = (idx & 3) * 8;
            int4 av = {0, 0, 0, 0};
            if (m < valid) av = *(const int4*)(Ab + (size_t)m * FD + k0 + ko);
            *(int4*)&As [m * LDT + ko] = av;
            *(int4*)&Bgs[m * LDT + ko] = *(const int4*)(Bgb + (size_t)m * FD + k0 + ko);
            *(int4*)&Bus[m * LDT + ko] = *(const int4*)(Bub + (size_t)m * FD + k0 + ko);
        }
        __syncthreads();
        bf16x8 af[4], bgf[4], buf[4];
        for (int i = 0; i < 4; i++) af[i]  = *(const bf16x8*)&As [(wm*64 + i*16 + lr) * LDT + qd*8];
        for (int j = 0; j < 4; j++) bgf[j] = *(const bf16x8*)&Bgs[(wn*64 + j*16 + lr) * LDT + qd*8];
        for (int j = 0; j < 4; j++) buf[j] = *(const bf16x8*)&Bus[(wn*64 + j*16 + lr) * LDT + qd*8];
        for (int i = 0; i < 4; i++)
            for (int j = 0; j < 4; j++) {
                accg[i][j] = __builtin_amdgcn_mfma_f32_16x16x32_bf16(af[i], bgf[j], accg[i][j], 0, 0, 0);
                accu[i][j] = __builtin_amdgcn_mfma_f32_16x16x32_bf16(af[i], buf[j], accu[i][j], 0, 0, 0);
            }
        __syncthreads();
    }
    for (int i = 0; i < 4; i++) {
        int rb = wm * 64 + i * 16 + qd * 4;
        for (int r = 0; r < 4; r++) {
            int m = rb + r;
            if (m >= valid) continue;
            size_t orow = (size_t)(base + row0 + m) * HD;
            for (int j = 0; j < 4; j++) {
                int n = n0 + wn * 64 + j * 16 + lr;
                float g = accg[i][j][r] + bg[e * HD + n];
                float u = accu[i][j][r] + bu[e * HD + n];
                float h = g * u / (1.f + __expf(-g));   // silu(g)*u
                Hbuf[orow + n] = (bf16)h;
            }
        }
    }
}

// GEMM2: H2 = relu(Hbuf@W1 + b1); K=HD, N=HD (grid.y=8)
__global__ __launch_bounds__(256) void k_gemm2(
    const bf16* __restrict__ Ain, const bf16* __restrict__ Bt, const float* __restrict__ bias,
    bf16* __restrict__ Out,
    const int* __restrict__ tileE, const int* __restrict__ tileR,
    const int* __restrict__ off, const int* __restrict__ ntp)
{
    if (blockIdx.x >= *ntp) return;
    __shared__ bf16 As[BM * LDT];
    __shared__ bf16 Bs[BN * LDT];
    int e    = tileE[blockIdx.x];
    int row0 = tileR[blockIdx.x] * BM;
    int base = off[e];
    int valid = off[e + 1] - base - row0; if (valid > BM) valid = BM;
    int n0 = blockIdx.y * BN;
    int tid = threadIdx.x;
    int lane = tid & 63, wv = tid >> 6;
    int wm = wv & 1, wn = wv >> 1;
    int lr = lane & 15, qd = lane >> 4;

    f32x4 acc[4][4] = {};
    const bf16* Ab = Ain + (size_t)(base + row0) * HD;
    const bf16* Bb = Bt  + ((size_t)e * HD + n0) * HD;

    for (int k0 = 0; k0 < HD; k0 += BK) {
        for (int c = 0; c < 2; c++) {
            int idx = tid + c * 256;
            int m = idx >> 2, ko = (idx & 3) * 8;
            int4 av = {0, 0, 0, 0};
            if (m < valid) av = *(const int4*)(Ab + (size_t)m * HD + k0 + ko);
            *(int4*)&As[m * LDT + ko] = av;
            *(int4*)&Bs[m * LDT + ko] = *(const int4*)(Bb + (size_t)m * HD + k0 + ko);
        }
        __syncthreads();
        bf16x8 af[4], bfr[4];
        for (int i = 0; i < 4; i++) af[i]  = *(const bf16x8*)&As[(wm*64 + i*16 + lr) * LDT + qd*8];
        for (int j = 0; j < 4; j++) bfr[j] = *(const bf16x8*)&Bs[(wn*64 + j*16 + lr) * LDT + qd*8];
        for (int i = 0; i < 4; i++)
            for (int j = 0; j < 4; j++)
                acc[i][j] = __builtin_amdgcn_mfma_f32_16x16x32_bf16(af[i], bfr[j], acc[i][j], 0, 0, 0);
        __syncthreads();
    }
    for (int i = 0; i < 4; i++) {
        int rb = wm * 64 + i * 16 + qd * 4;
        for (int r = 0; r < 4; r++) {
            int m = rb + r;
            if (m >= valid) continue;
            size_t orow = (size_t)(base + row0 + m) * HD;
            for (int j = 0; j < 4; j++) {
                int n = n0 + wn * 64 + j * 16 + lr;
                float v = acc[i][j][r] + bias[e * HD + n];
                Out[orow + n] = (bf16)(v > 0.f ? v : 0.f);
            }
        }
    }
}

// GEMM3: out[perm] = H2@W2 + b2; K=HD, N=OD (grid.y=2), fp32 scatter epilogue
__global__ __launch_bounds__(256) void k_gemm3(
    const bf16* __restrict__ Ain, const bf16* __restrict__ Bt, const float* __restrict__ bias,
    float* __restrict__ out, const int* __restrict__ perm,
    const int* __restrict__ tileE, const int* __restrict__ tileR,
    const int* __restrict__ off, const int* __restrict__ ntp)
{
    if (blockIdx.x >= *ntp) return;
    __shared__ bf16 As[BM * LDT];
    __shared__ bf16 Bs[BN * LDT];
    int e    = tileE[blockIdx.x];
    int row0 = tileR[blockIdx.x] * BM;
    int base = off[e];
    int valid = off[e + 1] - base - row0; if (valid > BM) valid = BM;
    int n0 = blockIdx.y * BN;
    int tid = threadIdx.x;
    int lane = tid & 63, wv = tid >> 6;
    int wm = wv & 1, wn = wv >> 1;
    int lr = lane & 15, qd = lane >> 4;

    f32x4 acc[4][4] = {};
    const bf16* Ab = Ain + (size_t)(base + row0) * HD;
    const bf16* Bb = Bt  + ((size_t)e * OD + n0) * HD;

    for (int k0 = 0; k0 < HD; k0 += BK) {
        for (int c = 0; c < 2; c++) {
            int idx = tid + c * 256;
            int m = idx >> 2, ko = (idx & 3) * 8;
            int4 av = {0, 0, 0, 0};
            if (m < valid) av = *(const int4*)(Ab + (size_t)m * HD + k0 + ko);
            *(int4*)&As[m * LDT + ko] = av;
            *(int4*)&Bs[m * LDT + ko] = *(const int4*)(Bb + (size_t)m * HD + k0 + ko);
        }
        __syncthreads();
        bf16x8 af[4], bfr[4];
        for (int i = 0; i < 4; i++) af[i]  = *(const bf16x8*)&As[(wm*64 + i*16 + lr) * LDT + qd*8];
        for (int j = 0; j < 4; j++) bfr[j] = *(const bf16x8*)&Bs[(wn*64 + j*16 + lr) * LDT + qd*8];
        for (int i = 0; i < 4; i++)
            for (int j = 0; j < 4; j++)
                acc[i][j] = __builtin_amdgcn_mfma_f32_16x16x32_bf16(af[i], bfr[j], acc[i][j], 0, 0, 0);
        __syncthreads();
    }
    for (int i = 0; i < 4; i++) {
        int rb = wm * 64 + i * 16 + qd * 4;
        for (int r = 0; r < 4; r++) {
            int m = rb + r;
            if (m >= valid) continue;
            int tok = perm[base + row0 + m];
            size_t orow = (size_t)tok * OD;
            for (int j = 0; j < 4; j++) {
                int n = n0 + wn * 64 + j * 16 + lr;
                out[orow + n] = acc[i][j][r] + bias[e * OD + n];
            }
        }
    }
}

// ---------------- launch ----------------
extern "C" void kernel_launch(void* const* d_in, const int* in_sizes, int n_in,
                              void* d_out, int out_size, void* d_ws, size_t ws_size,
                              hipStream_t stream) {
    const float* x   = (const float*)d_in[0];
    const int*   sel = (const int*)d_in[1];
    const float* Wg  = (const float*)d_in[2];
    const float* bg  = (const float*)d_in[3];
    const float* Wu  = (const float*)d_in[4];
    const float* bu  = (const float*)d_in[5];
    const float* W1  = (const float*)d_in[6];
    const float* b1  = (const float*)d_in[7];
    const float* W2  = (const float*)d_in[8];
    const float* b2  = (const float*)d_in[9];
    float* out = (float*)d_out;

    char* ws = (char*)d_ws;
    int* cnt   = (int*)(ws + O_CNT);
    int* cur   = (int*)(ws + O_CUR);
    int* off   = (int*)(ws + O_OFF);
    int* nt    = (int*)(ws + O_NT);
    int* tileE = (int*)(ws + O_TE);
    int* tileR = (int*)(ws + O_TR);
    int* perm  = (int*)(ws + O_PERM);
    bf16* Xp   = (bf16*)(ws + O_XP);
    bf16* Wgt  = (bf16*)(ws + O_WG);
    bf16* Wut  = (bf16*)(ws + O_WU);
    bf16* W1t  = (bf16*)(ws + O_W1);
    bf16* W2t  = (bf16*)(ws + O_W2);
    bf16* Hbuf = (bf16*)(ws + O_H);
    bf16* H2   = (bf16*)(ws + O_H2);

    hipMemsetAsync(ws, 0, 256, stream);  // cnt, cur, off, nt

    k_hist   <<<NTOK / 256, 256, 0, stream>>>(sel, cnt);
    k_plan   <<<1, 64, 0, stream>>>(cnt, off, tileE, tileR, nt);
    k_scatter<<<NTOK / 256, 256, 0, stream>>>(sel, off, cur, perm);
    k_gather <<<NTOK * 64 / 256, 256, 0, stream>>>(x, perm, Xp);

    k_transpose<<<dim3(FD / 32, HD / 32, NEXP), 256, 0, stream>>>(Wg, Wgt, FD, HD);
    k_transpose<<<dim3(FD / 32, HD / 32, NEXP), 256, 0, stream>>>(Wu, Wut, FD, HD);
    k_transpose<<<dim3(HD / 32, HD / 32, NEXP), 256, 0, stream>>>(W1, W1t, HD, HD);
    k_transpose<<<dim3(HD / 32, OD / 32, NEXP), 256, 0, stream>>>(W2, W2t, HD, OD);

    k_gemm1<<<dim3(MAX_TILES, HD / BN), 256, 0, stream>>>(Xp, Wgt, Wut, bg, bu, Hbuf,
                                                          tileE, tileR, off, nt);
    k_gemm2<<<dim3(MAX_TILES, HD / BN), 256, 0, stream>>>(Hbuf, W1t, b1, H2,
                                                          tileE, tileR, off, nt);
    k_gemm3<<<dim3(MAX_TILES, OD / BN), 256, 0, stream>>>(H2, W2t, b2, out, perm,
                                                          tileE, tileR, off, nt);
}

// Round 4
// 664.744 us; speedup vs baseline: 1.0733x; 1.0733x over previous
//
#include <hip/hip_runtime.h>
#include <hip/hip_bf16.h>
#include <cstdint>
#include <cstddef>

// Problem constants
#define NTOK 32768   // P*N*K token-copies
#define FD   256     // input feature dim
#define HD   1024    // hidden dim
#define OD   256     // output dim
#define NEXP 8

// GEMM tiling
#define BM 128
#define BN 128
#define BK 32
#define MAX_TILES 272

typedef __bf16 bf16;
typedef __bf16 bf16x8 __attribute__((ext_vector_type(8)));
typedef __bf16 bf16x4 __attribute__((ext_vector_type(4)));
typedef float  f32x4  __attribute__((ext_vector_type(4)));

// async global->LDS, 16 B per lane. LDS dst MUST be wave-uniform base + lane*16.
__device__ __forceinline__ void cp16(const void* g, void* l) {
    __builtin_amdgcn_global_load_lds(
        (const __attribute__((address_space(1))) void*)g,
        (__attribute__((address_space(3))) void*)l, 16, 0, 0);
}

// ---- workspace layout (bytes) ----
static const size_t O_CNT  = 0;          // int[8]
static const size_t O_CUR  = 64;         // int[8]
static const size_t O_OFF  = 128;        // int[9]
static const size_t O_NT   = 192;        // int[1]
static const size_t O_TE   = 1024;       // int[512]
static const size_t O_TR   = 3072;       // int[512]
static const size_t O_PERM = 5120;       // int[NTOK]
static const size_t O_XP   = 136192;     // bf16 [NTOK][FD]    (16 MB)
static const size_t O_WG   = 16913408;   // bf16 [E][HD][FD]   (4 MB)
static const size_t O_WU   = 21107712;   // bf16 [E][HD][FD]   (4 MB)
static const size_t O_W1   = 25302016;   // bf16 [E][HD][HD]   (16 MB)
static const size_t O_W2   = 42079232;   // bf16 [E][OD][HD]   (4 MB)
static const size_t O_H    = 46273536;   // bf16 [NTOK][HD]    (64 MB)
static const size_t O_H2   = 113382400;  // bf16 [NTOK][HD]    (64 MB)

// ---------------- routing ----------------
__global__ void k_hist(const int* __restrict__ sel, int* __restrict__ cnt) {
    int t = blockIdx.x * 256 + threadIdx.x;
    if (t < NTOK) atomicAdd(&cnt[sel[t]], 1);
}

__global__ void k_plan(const int* __restrict__ cnt, int* __restrict__ off,
                       int* __restrict__ tileE, int* __restrict__ tileR,
                       int* __restrict__ nt) {
    if (threadIdx.x == 0 && blockIdx.x == 0) {
        int o = 0;
        for (int e = 0; e < NEXP; e++) { off[e] = o; o += cnt[e]; }
        off[NEXP] = o;
        int n = 0;
        for (int e = 0; e < NEXP; e++) {
            int c = cnt[e];
            int nte = (c + BM - 1) / BM;
            for (int r = 0; r < nte; r++) { tileE[n] = e; tileR[n] = r; n++; }
        }
        *nt = n;
    }
}

__global__ void k_scatter(const int* __restrict__ sel, const int* __restrict__ off,
                          int* __restrict__ cur, int* __restrict__ perm) {
    int t = blockIdx.x * 256 + threadIdx.x;
    if (t < NTOK) {
        int e = sel[t];
        int p = off[e] + atomicAdd(&cur[e], 1);
        perm[p] = t;
    }
}

__global__ void k_gather(const float* __restrict__ x, const int* __restrict__ perm,
                         bf16* __restrict__ Xp) {
    int gid = blockIdx.x * 256 + threadIdx.x;
    int pos = gid >> 6;
    int c   = gid & 63;
    int tok = perm[pos];
    float4 v = ((const float4*)x)[(size_t)tok * 64 + c];
    bf16x4 o;
    o.x = (bf16)v.x; o.y = (bf16)v.y; o.z = (bf16)v.z; o.w = (bf16)v.w;
    *(bf16x4*)&Xp[(size_t)pos * FD + c * 4] = o;
}

// W [E][K][N] fp32 -> Wt [E][N][K] bf16. 64x64 tiles, float4 in / bf16x8 out.
// Phase 1: 64 rows x 16 float4-chunks = 1024 items -> q<4.
// Phase 2: 64 n-vals x 8 bf16x8-chunks = 512 items -> q<2.  (q<4 was the R3 OOB bug)
__global__ void k_transpose(const float* __restrict__ W, bf16* __restrict__ Wt,
                            int K, int N) {
    __shared__ float tile[64][65];   // pad 65 -> 2-way max on both phases
    int k0 = blockIdx.x * 64, n0 = blockIdx.y * 64, e = blockIdx.z;
    const float* Ws = W  + (size_t)e * K * N;
    bf16*        Wd = Wt + (size_t)e * K * N;
    int t = threadIdx.x;
    for (int q = 0; q < 4; q++) {
        int lin = t + q * 256;
        int r = lin >> 4, c4 = (lin & 15) * 4;
        float4 v = *(const float4*)&Ws[(size_t)(k0 + r) * N + n0 + c4];
        tile[r][c4] = v.x; tile[r][c4+1] = v.y; tile[r][c4+2] = v.z; tile[r][c4+3] = v.w;
    }
    __syncthreads();
    for (int q = 0; q < 2; q++) {
        int lin = t + q * 256;
        int n = lin >> 3, k8 = (lin & 7) * 8;
        bf16x8 o;
        for (int i = 0; i < 8; i++) o[i] = (bf16)tile[k8 + i][n];
        *(bf16x8*)&Wd[(size_t)(n0 + n) * K + k0 + k8] = o;
    }
}

// ---------------- GEMM kernels ----------------
// MFMA 16x16x32 bf16:
//   A-frag: lane holds A[m=lane&15][k=(lane>>4)*8+j]
//   B-frag: lane holds B[k=(lane>>4)*8+j][n=lane&15]
//   C/D   : lane,reg r -> C[(lane>>4)*4+r][lane&15]
// LDS: unpadded [rows][BK] with XOR chunk swizzle:
//   LDS slot (row, s) holds global 16B-chunk j = s ^ ((row>>1)&3)
//   -> read slot = qd ^ ((row>>1)&3); start banks 16*(row&1)+4*slot => 2-way (free)

// GEMM1: Hbuf = silu(Xp@Wg + bg) * (Xp@Wu + bu); K=FD, grid.y = HD/BN
__global__ __launch_bounds__(256) void k_gemm1(
    const bf16* __restrict__ Xp, const bf16* __restrict__ Wgt, const bf16* __restrict__ Wut,
    const float* __restrict__ bg, const float* __restrict__ bu, bf16* __restrict__ Hbuf,
    const int* __restrict__ tileE, const int* __restrict__ tileR,
    const int* __restrict__ off, const int* __restrict__ ntp)
{
    if (blockIdx.x >= *ntp) return;
    __shared__ bf16 As [BM * BK];
    __shared__ bf16 Bgs[BN * BK];
    __shared__ bf16 Bus[BN * BK];
    int e    = tileE[blockIdx.x];
    int row0 = tileR[blockIdx.x] * BM;
    int base = off[e];
    int valid = off[e + 1] - base - row0; if (valid > BM) valid = BM;
    int n0 = blockIdx.y * BN;
    int tid = threadIdx.x;
    int lane = tid & 63, wv = tid >> 6;
    int wm = wv & 1, wn = wv >> 1;
    int lr = lane & 15, qd = lane >> 4;

    f32x4 accg[4][4] = {};
    f32x4 accu[4][4] = {};
    const bf16* Ab  = Xp  + (size_t)(base + row0) * FD;
    const bf16* Bgb = Wgt + ((size_t)e * HD + n0) * FD;
    const bf16* Bub = Wut + ((size_t)e * HD + n0) * FD;

    for (int k0 = 0; k0 < FD; k0 += BK) {
        for (int s = 0; s < 2; s++) {
            int ci = tid + s * 256;
            int m  = ci >> 2;
            int jg = (ci & 3) ^ ((m >> 1) & 3);
            int mc = m < valid ? m : valid - 1;   // clamp: no per-lane predication for lds-DMA
            cp16(Ab  + (size_t)mc * FD + k0 + jg * 8, &As [ci * 8]);
            cp16(Bgb + (size_t)m  * FD + k0 + jg * 8, &Bgs[ci * 8]);
            cp16(Bub + (size_t)m  * FD + k0 + jg * 8, &Bus[ci * 8]);
        }
        __syncthreads();
        bf16x8 af[4], bgf[4], buf[4];
        for (int i = 0; i < 4; i++) {
            int row = wm * 64 + i * 16 + lr;
            int sl  = qd ^ ((row >> 1) & 3);
            af[i] = *(const bf16x8*)&As[row * BK + sl * 8];
        }
        for (int j = 0; j < 4; j++) {
            int row = wn * 64 + j * 16 + lr;
            int sl  = qd ^ ((row >> 1) & 3);
            bgf[j] = *(const bf16x8*)&Bgs[row * BK + sl * 8];
            buf[j] = *(const bf16x8*)&Bus[row * BK + sl * 8];
        }
        for (int i = 0; i < 4; i++)
            for (int j = 0; j < 4; j++) {
                accg[i][j] = __builtin_amdgcn_mfma_f32_16x16x32_bf16(af[i], bgf[j], accg[i][j], 0, 0, 0);
                accu[i][j] = __builtin_amdgcn_mfma_f32_16x16x32_bf16(af[i], buf[j], accu[i][j], 0, 0, 0);
            }
        __syncthreads();
    }
    for (int i = 0; i < 4; i++) {
        int rb = wm * 64 + i * 16 + qd * 4;
        for (int r = 0; r < 4; r++) {
            int m = rb + r;
            if (m >= valid) continue;
            size_t orow = (size_t)(base + row0 + m) * HD;
            for (int j = 0; j < 4; j++) {
                int n = n0 + wn * 64 + j * 16 + lr;
                float g = accg[i][j][r] + bg[e * HD + n];
                float u = accu[i][j][r] + bu[e * HD + n];
                float h = g * u / (1.f + __expf(-g));   // silu(g)*u
                Hbuf[orow + n] = (bf16)h;
            }
        }
    }
}

// GEMM2: H2 = relu(Hbuf@W1 + b1); K=HD, grid.y = HD/BN
__global__ __launch_bounds__(256) void k_gemm2(
    const bf16* __restrict__ Ain, const bf16* __restrict__ Bt, const float* __restrict__ bias,
    bf16* __restrict__ Out,
    const int* __restrict__ tileE, const int* __restrict__ tileR,
    const int* __restrict__ off, const int* __restrict__ ntp)
{
    if (blockIdx.x >= *ntp) return;
    __shared__ bf16 As[BM * BK];
    __shared__ bf16 Bs[BN * BK];
    int e    = tileE[blockIdx.x];
    int row0 = tileR[blockIdx.x] * BM;
    int base = off[e];
    int valid = off[e + 1] - base - row0; if (valid > BM) valid = BM;
    int n0 = blockIdx.y * BN;
    int tid = threadIdx.x;
    int lane = tid & 63, wv = tid >> 6;
    int wm = wv & 1, wn = wv >> 1;
    int lr = lane & 15, qd = lane >> 4;

    f32x4 acc[4][4] = {};
    const bf16* Ab = Ain + (size_t)(base + row0) * HD;
    const bf16* Bb = Bt  + ((size_t)e * HD + n0) * HD;

    for (int k0 = 0; k0 < HD; k0 += BK) {
        for (int s = 0; s < 2; s++) {
            int ci = tid + s * 256;
            int m  = ci >> 2;
            int jg = (ci & 3) ^ ((m >> 1) & 3);
            int mc = m < valid ? m : valid - 1;
            cp16(Ab + (size_t)mc * HD + k0 + jg * 8, &As[ci * 8]);
            cp16(Bb + (size_t)m  * HD + k0 + jg * 8, &Bs[ci * 8]);
        }
        __syncthreads();
        bf16x8 af[4], bfr[4];
        for (int i = 0; i < 4; i++) {
            int row = wm * 64 + i * 16 + lr;
            int sl  = qd ^ ((row >> 1) & 3);
            af[i] = *(const bf16x8*)&As[row * BK + sl * 8];
        }
        for (int j = 0; j < 4; j++) {
            int row = wn * 64 + j * 16 + lr;
            int sl  = qd ^ ((row >> 1) & 3);
            bfr[j] = *(const bf16x8*)&Bs[row * BK + sl * 8];
        }
        for (int i = 0; i < 4; i++)
            for (int j = 0; j < 4; j++)
                acc[i][j] = __builtin_amdgcn_mfma_f32_16x16x32_bf16(af[i], bfr[j], acc[i][j], 0, 0, 0);
        __syncthreads();
    }
    for (int i = 0; i < 4; i++) {
        int rb = wm * 64 + i * 16 + qd * 4;
        for (int r = 0; r < 4; r++) {
            int m = rb + r;
            if (m >= valid) continue;
            size_t orow = (size_t)(base + row0 + m) * HD;
            for (int j = 0; j < 4; j++) {
                int n = n0 + wn * 64 + j * 16 + lr;
                float v = acc[i][j][r] + bias[e * HD + n];
                Out[orow + n] = (bf16)(v > 0.f ? v : 0.f);
            }
        }
    }
}

// GEMM3: out[perm] = H2@W2 + b2; K=HD, grid.y = OD/BN
__global__ __launch_bounds__(256) void k_gemm3(
    const bf16* __restrict__ Ain, const bf16* __restrict__ Bt, const float* __restrict__ bias,
    float* __restrict__ out, const int* __restrict__ perm,
    const int* __restrict__ tileE, const int* __restrict__ tileR,
    const int* __restrict__ off, const int* __restrict__ ntp)
{
    if (blockIdx.x >= *ntp) return;
    __shared__ bf16 As[BM * BK];
    __shared__ bf16 Bs[BN * BK];
    int e    = tileE[blockIdx.x];
    int row0 = tileR[blockIdx.x] * BM;
    int base = off[e];
    int valid = off[e + 1] - base - row0; if (valid > BM) valid = BM;
    int n0 = blockIdx.y * BN;
    int tid = threadIdx.x;
    int lane = tid & 63, wv = tid >> 6;
    int wm = wv & 1, wn = wv >> 1;
    int lr = lane & 15, qd = lane >> 4;

    f32x4 acc[4][4] = {};
    const bf16* Ab = Ain + (size_t)(base + row0) * HD;
    const bf16* Bb = Bt  + ((size_t)e * OD + n0) * HD;

    for (int k0 = 0; k0 < HD; k0 += BK) {
        for (int s = 0; s < 2; s++) {
            int ci = tid + s * 256;
            int m  = ci >> 2;
            int jg = (ci & 3) ^ ((m >> 1) & 3);
            int mc = m < valid ? m : valid - 1;
            cp16(Ab + (size_t)mc * HD + k0 + jg * 8, &As[ci * 8]);
            cp16(Bb + (size_t)m  * HD + k0 + jg * 8, &Bs[ci * 8]);
        }
        __syncthreads();
        bf16x8 af[4], bfr[4];
        for (int i = 0; i < 4; i++) {
            int row = wm * 64 + i * 16 + lr;
            int sl  = qd ^ ((row >> 1) & 3);
            af[i] = *(const bf16x8*)&As[row * BK + sl * 8];
        }
        for (int j = 0; j < 4; j++) {
            int row = wn * 64 + j * 16 + lr;
            int sl  = qd ^ ((row >> 1) & 3);
            bfr[j] = *(const bf16x8*)&Bs[row * BK + sl * 8];
        }
        for (int i = 0; i < 4; i++)
            for (int j = 0; j < 4; j++)
                acc[i][j] = __builtin_amdgcn_mfma_f32_16x16x32_bf16(af[i], bfr[j], acc[i][j], 0, 0, 0);
        __syncthreads();
    }
    for (int i = 0; i < 4; i++) {
        int rb = wm * 64 + i * 16 + qd * 4;
        for (int r = 0; r < 4; r++) {
            int m = rb + r;
            if (m >= valid) continue;
            int tok = perm[base + row0 + m];
            size_t orow = (size_t)tok * OD;
            for (int j = 0; j < 4; j++) {
                int n = n0 + wn * 64 + j * 16 + lr;
                out[orow + n] = acc[i][j][r] + bias[e * OD + n];
            }
        }
    }
}

// ---------------- launch ----------------
extern "C" void kernel_launch(void* const* d_in, const int* in_sizes, int n_in,
                              void* d_out, int out_size, void* d_ws, size_t ws_size,
                              hipStream_t stream) {
    const float* x   = (const float*)d_in[0];
    const int*   sel = (const int*)d_in[1];
    const float* Wg  = (const float*)d_in[2];
    const float* bg  = (const float*)d_in[3];
    const float* Wu  = (const float*)d_in[4];
    const float* bu  = (const float*)d_in[5];
    const float* W1  = (const float*)d_in[6];
    const float* b1  = (const float*)d_in[7];
    const float* W2  = (const float*)d_in[8];
    const float* b2  = (const float*)d_in[9];
    float* out = (float*)d_out;

    char* ws = (char*)d_ws;
    int* cnt   = (int*)(ws + O_CNT);
    int* cur   = (int*)(ws + O_CUR);
    int* off   = (int*)(ws + O_OFF);
    int* nt    = (int*)(ws + O_NT);
    int* tileE = (int*)(ws + O_TE);
    int* tileR = (int*)(ws + O_TR);
    int* perm  = (int*)(ws + O_PERM);
    bf16* Xp   = (bf16*)(ws + O_XP);
    bf16* Wgt  = (bf16*)(ws + O_WG);
    bf16* Wut  = (bf16*)(ws + O_WU);
    bf16* W1t  = (bf16*)(ws + O_W1);
    bf16* W2t  = (bf16*)(ws + O_W2);
    bf16* Hbuf = (bf16*)(ws + O_H);
    bf16* H2   = (bf16*)(ws + O_H2);

    hipMemsetAsync(ws, 0, 256, stream);

    k_hist   <<<NTOK / 256, 256, 0, stream>>>(sel, cnt);
    k_plan   <<<1, 64, 0, stream>>>(cnt, off, tileE, tileR, nt);
    k_scatter<<<NTOK / 256, 256, 0, stream>>>(sel, off, cur, perm);
    k_gather <<<NTOK * 64 / 256, 256, 0, stream>>>(x, perm, Xp);

    k_transpose<<<dim3(FD / 64, HD / 64, NEXP), 256, 0, stream>>>(Wg, Wgt, FD, HD);
    k_transpose<<<dim3(FD / 64, HD / 64, NEXP), 256, 0, stream>>>(Wu, Wut, FD, HD);
    k_transpose<<<dim3(HD / 64, HD / 64, NEXP), 256, 0, stream>>>(W1, W1t, HD, HD);
    k_transpose<<<dim3(HD / 64, OD / 64, NEXP), 256, 0, stream>>>(W2, W2t, HD, OD);

    k_gemm1<<<dim3(MAX_TILES, HD / BN), 256, 0, stream>>>(Xp, Wgt, Wut, bg, bu, Hbuf,
                                                          tileE, tileR, off, nt);
    k_gemm2<<<dim3(MAX_TILES, HD / BN), 256, 0, stream>>>(Hbuf, W1t, b1, H2,
                                                          tileE, tileR, off, nt);
    k_gemm3<<<dim3(MAX_TILES, OD / BN), 256, 0, stream>>>(H2, W2t, b2, out, perm,
                                                          tileE, tileR, off, nt);
}

// Round 5
// 640.088 us; speedup vs baseline: 1.1146x; 1.0385x over previous
//
#include <hip/hip_runtime.h>
#include <hip/hip_bf16.h>
#include <cstdint>
#include <cstddef>

// Problem constants
#define NTOK 32768   // P*N*K token-copies
#define FD   256     // input feature dim
#define HD   1024    // hidden dim
#define OD   256     // output dim
#define NEXP 8

// GEMM tiling
#define BM 128
#define BN 128
#define BK 32
#define MAX_TILES 272

typedef __bf16 bf16;
typedef __bf16 bf16x8 __attribute__((ext_vector_type(8)));
typedef __bf16 bf16x4 __attribute__((ext_vector_type(4)));
typedef float  f32x4  __attribute__((ext_vector_type(4)));

// async global->LDS, 16 B per lane. LDS dst MUST be wave-uniform base + lane*16.
__device__ __forceinline__ void cp16(const void* g, void* l) {
    __builtin_amdgcn_global_load_lds(
        (const __attribute__((address_space(1))) void*)g,
        (__attribute__((address_space(3))) void*)l, 16, 0, 0);
}

// ---- workspace layout (bytes) ----
static const size_t O_CNT  = 0;          // int[8]
static const size_t O_CUR  = 64;         // int[8]
static const size_t O_OFF  = 128;        // int[9]
static const size_t O_NT   = 192;        // int[1]
static const size_t O_TE   = 1024;       // int[512]
static const size_t O_TR   = 3072;       // int[512]
static const size_t O_PERM = 5120;       // int[NTOK]
static const size_t O_XP   = 136192;     // bf16 [NTOK][FD]    (16 MB)
static const size_t O_WG   = 16913408;   // bf16 [E][HD][FD]   (4 MB)
static const size_t O_WU   = 21107712;   // bf16 [E][HD][FD]   (4 MB)
static const size_t O_W1   = 25302016;   // bf16 [E][HD][HD]   (16 MB)
static const size_t O_W2   = 42079232;   // bf16 [E][OD][HD]   (4 MB)
static const size_t O_H    = 46273536;   // bf16 [NTOK][HD]    (64 MB) Hbuf
static const size_t O_H2   = 113382400;  // bf16 [NTOK][HD]    (64 MB) G (gate), later H2

// ---------------- routing ----------------
__global__ void k_hist(const int* __restrict__ sel, int* __restrict__ cnt) {
    int t = blockIdx.x * 256 + threadIdx.x;
    if (t < NTOK) atomicAdd(&cnt[sel[t]], 1);
}

__global__ void k_plan(const int* __restrict__ cnt, int* __restrict__ off,
                       int* __restrict__ tileE, int* __restrict__ tileR,
                       int* __restrict__ nt) {
    if (threadIdx.x == 0 && blockIdx.x == 0) {
        int o = 0;
        for (int e = 0; e < NEXP; e++) { off[e] = o; o += cnt[e]; }
        off[NEXP] = o;
        int n = 0;
        for (int e = 0; e < NEXP; e++) {
            int c = cnt[e];
            int nte = (c + BM - 1) / BM;
            for (int r = 0; r < nte; r++) { tileE[n] = e; tileR[n] = r; n++; }
        }
        *nt = n;
    }
}

__global__ void k_scatter(const int* __restrict__ sel, const int* __restrict__ off,
                          int* __restrict__ cur, int* __restrict__ perm) {
    int t = blockIdx.x * 256 + threadIdx.x;
    if (t < NTOK) {
        int e = sel[t];
        int p = off[e] + atomicAdd(&cur[e], 1);
        perm[p] = t;
    }
}

__global__ void k_gather(const float* __restrict__ x, const int* __restrict__ perm,
                         bf16* __restrict__ Xp) {
    int gid = blockIdx.x * 256 + threadIdx.x;
    int pos = gid >> 6;
    int c   = gid & 63;
    int tok = perm[pos];
    float4 v = ((const float4*)x)[(size_t)tok * 64 + c];
    bf16x4 o;
    o.x = (bf16)v.x; o.y = (bf16)v.y; o.z = (bf16)v.z; o.w = (bf16)v.w;
    *(bf16x4*)&Xp[(size_t)pos * FD + c * 4] = o;
}

// W [E][K][N] fp32 -> Wt [E][N][K] bf16. 64x64 tiles, float4 in / bf16x8 out.
__global__ void k_transpose(const float* __restrict__ W, bf16* __restrict__ Wt,
                            int K, int N) {
    __shared__ float tile[64][65];
    int k0 = blockIdx.x * 64, n0 = blockIdx.y * 64, e = blockIdx.z;
    const float* Ws = W  + (size_t)e * K * N;
    bf16*        Wd = Wt + (size_t)e * K * N;
    int t = threadIdx.x;
    for (int q = 0; q < 4; q++) {
        int lin = t + q * 256;
        int r = lin >> 4, c4 = (lin & 15) * 4;
        float4 v = *(const float4*)&Ws[(size_t)(k0 + r) * N + n0 + c4];
        tile[r][c4] = v.x; tile[r][c4+1] = v.y; tile[r][c4+2] = v.z; tile[r][c4+3] = v.w;
    }
    __syncthreads();
    for (int q = 0; q < 2; q++) {   // 64 n * 8 chunks = 512 items
        int lin = t + q * 256;
        int n = lin >> 3, k8 = (lin & 7) * 8;
        bf16x8 o;
        for (int i = 0; i < 8; i++) o[i] = (bf16)tile[k8 + i][n];
        *(bf16x8*)&Wd[(size_t)(n0 + n) * K + k0 + k8] = o;
    }
}

// ---------------- GEMM kernels ----------------
// MFMA 16x16x32 bf16 layouts (HW-verified):
//   A-frag: lane holds A[m=lane&15][k=(lane>>4)*8+j]
//   B-frag: lane holds B[k=(lane>>4)*8+j][n=lane&15]
//   C/D   : lane,reg r -> C[(lane>>4)*4+r][lane&15]
// LDS: unpadded [rows][BK], XOR chunk swizzle: slot s holds chunk s^((row>>1)&3);
//   read slot = qd^((row>>1)&3) -> max 2-way bank aliasing (free).
// __launch_bounds__(256,3): 3 waves/EU -> <=170 unified VGPR+AGPR -> 3 blocks/CU.

#define GEMM_PROLOGUE(KDIM)                                                    \
    if (blockIdx.x >= *ntp) return;                                            \
    __shared__ bf16 As[BM * BK];                                               \
    __shared__ bf16 Bs[BN * BK];                                               \
    int e    = tileE[blockIdx.x];                                              \
    int row0 = tileR[blockIdx.x] * BM;                                         \
    int base = off[e];                                                         \
    int valid = off[e + 1] - base - row0; if (valid > BM) valid = BM;          \
    int n0 = blockIdx.y * BN;                                                  \
    int tid = threadIdx.x;                                                     \
    int lane = tid & 63, wv = tid >> 6;                                        \
    int wm = wv & 1, wn = wv >> 1;                                             \
    int lr = lane & 15, qd = lane >> 4;                                        \
    f32x4 acc[4][4] = {};

#define GEMM_KLOOP(KDIM)                                                       \
    for (int k0 = 0; k0 < (KDIM); k0 += BK) {                                  \
        for (int s = 0; s < 2; s++) {                                          \
            int ci = tid + s * 256;                                            \
            int m  = ci >> 2;                                                  \
            int jg = (ci & 3) ^ ((m >> 1) & 3);                                \
            int mc = m < valid ? m : valid - 1;                                \
            cp16(Ab + (size_t)mc * (KDIM) + k0 + jg * 8, &As[ci * 8]);         \
            cp16(Bb + (size_t)m  * (KDIM) + k0 + jg * 8, &Bs[ci * 8]);         \
        }                                                                      \
        __syncthreads();                                                       \
        bf16x8 af[4], bfr[4];                                                  \
        for (int i = 0; i < 4; i++) {                                          \
            int row = wm * 64 + i * 16 + lr;                                   \
            int sl  = qd ^ ((row >> 1) & 3);                                   \
            af[i] = *(const bf16x8*)&As[row * BK + sl * 8];                    \
        }                                                                      \
        for (int j = 0; j < 4; j++) {                                          \
            int row = wn * 64 + j * 16 + lr;                                   \
            int sl  = qd ^ ((row >> 1) & 3);                                   \
            bfr[j] = *(const bf16x8*)&Bs[row * BK + sl * 8];                   \
        }                                                                      \
        for (int i = 0; i < 4; i++)                                            \
            for (int j = 0; j < 4; j++)                                        \
                acc[i][j] = __builtin_amdgcn_mfma_f32_16x16x32_bf16(           \
                    af[i], bfr[j], acc[i][j], 0, 0, 0);                        \
        __syncthreads();                                                       \
    }

// k_gate: G = Xp@Wg + bg (bf16), G lives in the O_H2 region (dead until gemm2)
__global__ __launch_bounds__(256, 3) void k_gate(
    const bf16* __restrict__ Xp, const bf16* __restrict__ Wgt,
    const float* __restrict__ bg, bf16* __restrict__ G,
    const int* __restrict__ tileE, const int* __restrict__ tileR,
    const int* __restrict__ off, const int* __restrict__ ntp)
{
    GEMM_PROLOGUE(FD)
    const bf16* Ab = Xp  + (size_t)(base + row0) * FD;
    const bf16* Bb = Wgt + ((size_t)e * HD + n0) * FD;
    GEMM_KLOOP(FD)
    for (int i = 0; i < 4; i++) {
        int rb = wm * 64 + i * 16 + qd * 4;
        for (int r = 0; r < 4; r++) {
            int m = rb + r;
            if (m >= valid) continue;
            size_t orow = (size_t)(base + row0 + m) * HD;
            for (int j = 0; j < 4; j++) {
                int n = n0 + wn * 64 + j * 16 + lr;
                G[orow + n] = (bf16)(acc[i][j][r] + bg[e * HD + n]);
            }
        }
    }
}

// k_up: u = Xp@Wu + bu; Hbuf = silu(G)*u
__global__ __launch_bounds__(256, 3) void k_up(
    const bf16* __restrict__ Xp, const bf16* __restrict__ Wut,
    const float* __restrict__ bu, const bf16* __restrict__ G,
    bf16* __restrict__ Hbuf,
    const int* __restrict__ tileE, const int* __restrict__ tileR,
    const int* __restrict__ off, const int* __restrict__ ntp)
{
    GEMM_PROLOGUE(FD)
    const bf16* Ab = Xp  + (size_t)(base + row0) * FD;
    const bf16* Bb = Wut + ((size_t)e * HD + n0) * FD;
    GEMM_KLOOP(FD)
    for (int i = 0; i < 4; i++) {
        int rb = wm * 64 + i * 16 + qd * 4;
        for (int r = 0; r < 4; r++) {
            int m = rb + r;
            if (m >= valid) continue;
            size_t orow = (size_t)(base + row0 + m) * HD;
            for (int j = 0; j < 4; j++) {
                int n = n0 + wn * 64 + j * 16 + lr;
                float u = acc[i][j][r] + bu[e * HD + n];
                float g = (float)G[orow + n];
                float h = g * u / (1.f + __expf(-g));   // silu(g)*u
                Hbuf[orow + n] = (bf16)h;
            }
        }
    }
}

// gemm2: H2 = relu(Hbuf@W1 + b1)  (H2 overwrites the dead G region)
__global__ __launch_bounds__(256, 3) void k_gemm2(
    const bf16* __restrict__ Ain, const bf16* __restrict__ Bt, const float* __restrict__ bias,
    bf16* __restrict__ Out,
    const int* __restrict__ tileE, const int* __restrict__ tileR,
    const int* __restrict__ off, const int* __restrict__ ntp)
{
    GEMM_PROLOGUE(HD)
    const bf16* Ab = Ain + (size_t)(base + row0) * HD;
    const bf16* Bb = Bt  + ((size_t)e * HD + n0) * HD;
    GEMM_KLOOP(HD)
    for (int i = 0; i < 4; i++) {
        int rb = wm * 64 + i * 16 + qd * 4;
        for (int r = 0; r < 4; r++) {
            int m = rb + r;
            if (m >= valid) continue;
            size_t orow = (size_t)(base + row0 + m) * HD;
            for (int j = 0; j < 4; j++) {
                int n = n0 + wn * 64 + j * 16 + lr;
                float v = acc[i][j][r] + bias[e * HD + n];
                Out[orow + n] = (bf16)(v > 0.f ? v : 0.f);
            }
        }
    }
}

// gemm3: out[perm] = H2@W2 + b2 (fp32 scatter)
__global__ __launch_bounds__(256, 3) void k_gemm3(
    const bf16* __restrict__ Ain, const bf16* __restrict__ Bt, const float* __restrict__ bias,
    float* __restrict__ out, const int* __restrict__ perm,
    const int* __restrict__ tileE, const int* __restrict__ tileR,
    const int* __restrict__ off, const int* __restrict__ ntp)
{
    GEMM_PROLOGUE(HD)
    const bf16* Ab = Ain + (size_t)(base + row0) * HD;
    const bf16* Bb = Bt  + ((size_t)e * OD + n0) * HD;
    GEMM_KLOOP(HD)
    for (int i = 0; i < 4; i++) {
        int rb = wm * 64 + i * 16 + qd * 4;
        for (int r = 0; r < 4; r++) {
            int m = rb + r;
            if (m >= valid) continue;
            int tok = perm[base + row0 + m];
            size_t orow = (size_t)tok * OD;
            for (int j = 0; j < 4; j++) {
                int n = n0 + wn * 64 + j * 16 + lr;
                out[orow + n] = acc[i][j][r] + bias[e * OD + n];
            }
        }
    }
}

// ---------------- launch ----------------
extern "C" void kernel_launch(void* const* d_in, const int* in_sizes, int n_in,
                              void* d_out, int out_size, void* d_ws, size_t ws_size,
                              hipStream_t stream) {
    const float* x   = (const float*)d_in[0];
    const int*   sel = (const int*)d_in[1];
    const float* Wg  = (const float*)d_in[2];
    const float* bg  = (const float*)d_in[3];
    const float* Wu  = (const float*)d_in[4];
    const float* bu  = (const float*)d_in[5];
    const float* W1  = (const float*)d_in[6];
    const float* b1  = (const float*)d_in[7];
    const float* W2  = (const float*)d_in[8];
    const float* b2  = (const float*)d_in[9];
    float* out = (float*)d_out;

    char* ws = (char*)d_ws;
    int* cnt   = (int*)(ws + O_CNT);
    int* cur   = (int*)(ws + O_CUR);
    int* off   = (int*)(ws + O_OFF);
    int* nt    = (int*)(ws + O_NT);
    int* tileE = (int*)(ws + O_TE);
    int* tileR = (int*)(ws + O_TR);
    int* perm  = (int*)(ws + O_PERM);
    bf16* Xp   = (bf16*)(ws + O_XP);
    bf16* Wgt  = (bf16*)(ws + O_WG);
    bf16* Wut  = (bf16*)(ws + O_WU);
    bf16* W1t  = (bf16*)(ws + O_W1);
    bf16* W2t  = (bf16*)(ws + O_W2);
    bf16* Hbuf = (bf16*)(ws + O_H);
    bf16* Gbuf = (bf16*)(ws + O_H2);   // G during SwiGLU phase
    bf16* H2   = (bf16*)(ws + O_H2);   // overwritten by gemm2 after G is dead

    hipMemsetAsync(ws, 0, 256, stream);

    k_hist   <<<NTOK / 256, 256, 0, stream>>>(sel, cnt);
    k_plan   <<<1, 64, 0, stream>>>(cnt, off, tileE, tileR, nt);
    k_scatter<<<NTOK / 256, 256, 0, stream>>>(sel, off, cur, perm);
    k_gather <<<NTOK * 64 / 256, 256, 0, stream>>>(x, perm, Xp);

    k_transpose<<<dim3(FD / 64, HD / 64, NEXP), 256, 0, stream>>>(Wg, Wgt, FD, HD);
    k_transpose<<<dim3(FD / 64, HD / 64, NEXP), 256, 0, stream>>>(Wu, Wut, FD, HD);
    k_transpose<<<dim3(HD / 64, HD / 64, NEXP), 256, 0, stream>>>(W1, W1t, HD, HD);
    k_transpose<<<dim3(HD / 64, OD / 64, NEXP), 256, 0, stream>>>(W2, W2t, HD, OD);

    k_gate <<<dim3(MAX_TILES, HD / BN), 256, 0, stream>>>(Xp, Wgt, bg, Gbuf,
                                                          tileE, tileR, off, nt);
    k_up   <<<dim3(MAX_TILES, HD / BN), 256, 0, stream>>>(Xp, Wut, bu, Gbuf, Hbuf,
                                                          tileE, tileR, off, nt);
    k_gemm2<<<dim3(MAX_TILES, HD / BN), 256, 0, stream>>>(Hbuf, W1t, b1, H2,
                                                          tileE, tileR, off, nt);
    k_gemm3<<<dim3(MAX_TILES, OD / BN), 256, 0, stream>>>(H2, W2t, b2, out, perm,
                                                          tileE, tileR, off, nt);
}

// Round 6
// 398.970 us; speedup vs baseline: 1.7883x; 1.6044x over previous
//
#include <hip/hip_runtime.h>
#include <hip/hip_bf16.h>
#include <cstdint>
#include <cstddef>

// Problem constants
#define NTOK 32768   // P*N*K token-copies
#define FD   256     // input feature dim
#define HD   1024    // hidden dim
#define OD   256     // output dim
#define NEXP 8

// GEMM tiling
#define BM 128
#define BN 128
#define BK 32
#define MAX_TILES 272

typedef __bf16 bf16;
typedef __bf16 bf16x8 __attribute__((ext_vector_type(8)));
typedef __bf16 bf16x4 __attribute__((ext_vector_type(4)));
typedef float  f32x4  __attribute__((ext_vector_type(4)));

// async global->LDS, 16 B per lane. LDS dst MUST be wave-uniform base + lane*16.
__device__ __forceinline__ void cp16(const void* g, void* l) {
    __builtin_amdgcn_global_load_lds(
        (const __attribute__((address_space(1))) void*)g,
        (__attribute__((address_space(3))) void*)l, 16, 0, 0);
}

// ---- workspace layout (bytes) ----
static const size_t O_CNT  = 0;          // int[8]
static const size_t O_CUR  = 64;         // int[8]
static const size_t O_OFF  = 128;        // int[9]
static const size_t O_NT   = 192;        // int[1]
static const size_t O_TE   = 1024;       // int[512]
static const size_t O_TR   = 3072;       // int[512]
static const size_t O_PERM = 5120;       // int[NTOK]
static const size_t O_XP   = 136192;     // bf16 [NTOK][FD]    (16 MB)
static const size_t O_WG   = 16913408;   // bf16 [E][HD][FD]   (4 MB)
static const size_t O_WU   = 21107712;   // bf16 [E][HD][FD]   (4 MB)
static const size_t O_W1   = 25302016;   // bf16 [E][HD][HD]   (16 MB)
static const size_t O_W2   = 42079232;   // bf16 [E][OD][HD]   (4 MB)
static const size_t O_H    = 46273536;   // bf16 [NTOK][HD]    (64 MB) Hbuf
static const size_t O_H2   = 113382400;  // bf16 [NTOK][HD]    (64 MB) G (gate), later H2

// ---------------- routing ----------------
// Two-level histogram: LDS per-block counts, then 8 global atomics per block.
// (32768 same-address atomics was 125 us -> ~5 us this way.)
__global__ void k_hist(const int* __restrict__ sel, int* __restrict__ cnt) {
    __shared__ int lcnt[NEXP];
    if (threadIdx.x < NEXP) lcnt[threadIdx.x] = 0;
    __syncthreads();
    int t = blockIdx.x * 256 + threadIdx.x;   // NTOK % 256 == 0
    atomicAdd(&lcnt[sel[t]], 1);
    __syncthreads();
    if (threadIdx.x < NEXP) atomicAdd(&cnt[threadIdx.x], lcnt[threadIdx.x]);
}

__global__ void k_plan(const int* __restrict__ cnt, int* __restrict__ off,
                       int* __restrict__ tileE, int* __restrict__ tileR,
                       int* __restrict__ nt) {
    if (threadIdx.x == 0 && blockIdx.x == 0) {
        int o = 0;
        for (int e = 0; e < NEXP; e++) { off[e] = o; o += cnt[e]; }
        off[NEXP] = o;
        int n = 0;
        for (int e = 0; e < NEXP; e++) {
            int c = cnt[e];
            int nte = (c + BM - 1) / BM;
            for (int r = 0; r < nte; r++) { tileE[n] = e; tileR[n] = r; n++; }
        }
        *nt = n;
    }
}

// Per-block rank via LDS histogram, one global atomic per (block,expert) to
// reserve a base. Order within an expert is nondeterministic (ok: the final
// scatter by perm is order-independent).
__global__ void k_scatter(const int* __restrict__ sel, const int* __restrict__ off,
                          int* __restrict__ cur, int* __restrict__ perm) {
    __shared__ int lcnt[NEXP];
    __shared__ int lbase[NEXP];
    if (threadIdx.x < NEXP) lcnt[threadIdx.x] = 0;
    __syncthreads();
    int t = blockIdx.x * 256 + threadIdx.x;
    int e = sel[t];
    int rank = atomicAdd(&lcnt[e], 1);
    __syncthreads();
    if (threadIdx.x < NEXP)
        lbase[threadIdx.x] = atomicAdd(&cur[threadIdx.x], lcnt[threadIdx.x]);
    __syncthreads();
    perm[off[e] + lbase[e] + rank] = t;
}

__global__ void k_gather(const float* __restrict__ x, const int* __restrict__ perm,
                         bf16* __restrict__ Xp) {
    int gid = blockIdx.x * 256 + threadIdx.x;
    int pos = gid >> 6;
    int c   = gid & 63;
    int tok = perm[pos];
    float4 v = ((const float4*)x)[(size_t)tok * 64 + c];
    bf16x4 o;
    o.x = (bf16)v.x; o.y = (bf16)v.y; o.z = (bf16)v.z; o.w = (bf16)v.w;
    *(bf16x4*)&Xp[(size_t)pos * FD + c * 4] = o;
}

// W [E][K][N] fp32 -> Wt [E][N][K] bf16. 64x64 tiles, float4 in / bf16x8 out.
__global__ void k_transpose(const float* __restrict__ W, bf16* __restrict__ Wt,
                            int K, int N) {
    __shared__ float tile[64][65];
    int k0 = blockIdx.x * 64, n0 = blockIdx.y * 64, e = blockIdx.z;
    const float* Ws = W  + (size_t)e * K * N;
    bf16*        Wd = Wt + (size_t)e * K * N;
    int t = threadIdx.x;
    for (int q = 0; q < 4; q++) {
        int lin = t + q * 256;
        int r = lin >> 4, c4 = (lin & 15) * 4;
        float4 v = *(const float4*)&Ws[(size_t)(k0 + r) * N + n0 + c4];
        tile[r][c4] = v.x; tile[r][c4+1] = v.y; tile[r][c4+2] = v.z; tile[r][c4+3] = v.w;
    }
    __syncthreads();
    for (int q = 0; q < 2; q++) {   // 64 n * 8 chunks = 512 items
        int lin = t + q * 256;
        int n = lin >> 3, k8 = (lin & 7) * 8;
        bf16x8 o;
        for (int i = 0; i < 8; i++) o[i] = (bf16)tile[k8 + i][n];
        *(bf16x8*)&Wd[(size_t)(n0 + n) * K + k0 + k8] = o;
    }
}

// ---------------- GEMM kernels ----------------
// MFMA 16x16x32 bf16 layouts (HW-verified):
//   A-frag: lane holds A[m=lane&15][k=(lane>>4)*8+j]
//   B-frag: lane holds B[k=(lane>>4)*8+j][n=lane&15]
//   C/D   : lane,reg r -> C[(lane>>4)*4+r][lane&15]
// LDS: unpadded [rows][BK], XOR chunk swizzle: slot s holds chunk s^((row>>1)&3);
//   read slot = qd^((row>>1)&3) -> max 2-way bank aliasing (free).
// __launch_bounds__(256,3): 3 waves/EU target for occupancy.

#define GEMM_PROLOGUE(KDIM)                                                    \
    if (blockIdx.x >= *ntp) return;                                            \
    __shared__ bf16 As[BM * BK];                                               \
    __shared__ bf16 Bs[BN * BK];                                               \
    int e    = tileE[blockIdx.x];                                              \
    int row0 = tileR[blockIdx.x] * BM;                                         \
    int base = off[e];                                                         \
    int valid = off[e + 1] - base - row0; if (valid > BM) valid = BM;          \
    int n0 = blockIdx.y * BN;                                                  \
    int tid = threadIdx.x;                                                     \
    int lane = tid & 63, wv = tid >> 6;                                        \
    int wm = wv & 1, wn = wv >> 1;                                             \
    int lr = lane & 15, qd = lane >> 4;                                        \
    f32x4 acc[4][4] = {};

#define GEMM_KLOOP(KDIM)                                                       \
    for (int k0 = 0; k0 < (KDIM); k0 += BK) {                                  \
        for (int s = 0; s < 2; s++) {                                          \
            int ci = tid + s * 256;                                            \
            int m  = ci >> 2;                                                  \
            int jg = (ci & 3) ^ ((m >> 1) & 3);                                \
            int mc = m < valid ? m : valid - 1;                                \
            cp16(Ab + (size_t)mc * (KDIM) + k0 + jg * 8, &As[ci * 8]);         \
            cp16(Bb + (size_t)m  * (KDIM) + k0 + jg * 8, &Bs[ci * 8]);         \
        }                                                                      \
        __syncthreads();                                                       \
        bf16x8 af[4], bfr[4];                                                  \
        for (int i = 0; i < 4; i++) {                                          \
            int row = wm * 64 + i * 16 + lr;                                   \
            int sl  = qd ^ ((row >> 1) & 3);                                   \
            af[i] = *(const bf16x8*)&As[row * BK + sl * 8];                    \
        }                                                                      \
        for (int j = 0; j < 4; j++) {                                          \
            int row = wn * 64 + j * 16 + lr;                                   \
            int sl  = qd ^ ((row >> 1) & 3);                                   \
            bfr[j] = *(const bf16x8*)&Bs[row * BK + sl * 8];                   \
        }                                                                      \
        for (int i = 0; i < 4; i++)                                            \
            for (int j = 0; j < 4; j++)                                        \
                acc[i][j] = __builtin_amdgcn_mfma_f32_16x16x32_bf16(           \
                    af[i], bfr[j], acc[i][j], 0, 0, 0);                        \
        __syncthreads();                                                       \
    }

// k_gate: G = Xp@Wg + bg (bf16), G lives in the O_H2 region (dead until gemm2)
__global__ __launch_bounds__(256, 3) void k_gate(
    const bf16* __restrict__ Xp, const bf16* __restrict__ Wgt,
    const float* __restrict__ bg, bf16* __restrict__ G,
    const int* __restrict__ tileE, const int* __restrict__ tileR,
    const int* __restrict__ off, const int* __restrict__ ntp)
{
    GEMM_PROLOGUE(FD)
    const bf16* Ab = Xp  + (size_t)(base + row0) * FD;
    const bf16* Bb = Wgt + ((size_t)e * HD + n0) * FD;
    GEMM_KLOOP(FD)
    for (int i = 0; i < 4; i++) {
        int rb = wm * 64 + i * 16 + qd * 4;
        for (int r = 0; r < 4; r++) {
            int m = rb + r;
            if (m >= valid) continue;
            size_t orow = (size_t)(base + row0 + m) * HD;
            for (int j = 0; j < 4; j++) {
                int n = n0 + wn * 64 + j * 16 + lr;
                G[orow + n] = (bf16)(acc[i][j][r] + bg[e * HD + n]);
            }
        }
    }
}

// k_up: u = Xp@Wu + bu; Hbuf = silu(G)*u
__global__ __launch_bounds__(256, 3) void k_up(
    const bf16* __restrict__ Xp, const bf16* __restrict__ Wut,
    const float* __restrict__ bu, const bf16* __restrict__ G,
    bf16* __restrict__ Hbuf,
    const int* __restrict__ tileE, const int* __restrict__ tileR,
    const int* __restrict__ off, const int* __restrict__ ntp)
{
    GEMM_PROLOGUE(FD)
    const bf16* Ab = Xp  + (size_t)(base + row0) * FD;
    const bf16* Bb = Wut + ((size_t)e * HD + n0) * FD;
    GEMM_KLOOP(FD)
    for (int i = 0; i < 4; i++) {
        int rb = wm * 64 + i * 16 + qd * 4;
        for (int r = 0; r < 4; r++) {
            int m = rb + r;
            if (m >= valid) continue;
            size_t orow = (size_t)(base + row0 + m) * HD;
            for (int j = 0; j < 4; j++) {
                int n = n0 + wn * 64 + j * 16 + lr;
                float u = acc[i][j][r] + bu[e * HD + n];
                float g = (float)G[orow + n];
                float h = g * u / (1.f + __expf(-g));   // silu(g)*u
                Hbuf[orow + n] = (bf16)h;
            }
        }
    }
}

// gemm2: H2 = relu(Hbuf@W1 + b1)  (H2 overwrites the dead G region)
__global__ __launch_bounds__(256, 3) void k_gemm2(
    const bf16* __restrict__ Ain, const bf16* __restrict__ Bt, const float* __restrict__ bias,
    bf16* __restrict__ Out,
    const int* __restrict__ tileE, const int* __restrict__ tileR,
    const int* __restrict__ off, const int* __restrict__ ntp)
{
    GEMM_PROLOGUE(HD)
    const bf16* Ab = Ain + (size_t)(base + row0) * HD;
    const bf16* Bb = Bt  + ((size_t)e * HD + n0) * HD;
    GEMM_KLOOP(HD)
    for (int i = 0; i < 4; i++) {
        int rb = wm * 64 + i * 16 + qd * 4;
        for (int r = 0; r < 4; r++) {
            int m = rb + r;
            if (m >= valid) continue;
            size_t orow = (size_t)(base + row0 + m) * HD;
            for (int j = 0; j < 4; j++) {
                int n = n0 + wn * 64 + j * 16 + lr;
                float v = acc[i][j][r] + bias[e * HD + n];
                Out[orow + n] = (bf16)(v > 0.f ? v : 0.f);
            }
        }
    }
}

// gemm3: out[perm] = H2@W2 + b2 (fp32 scatter)
__global__ __launch_bounds__(256, 3) void k_gemm3(
    const bf16* __restrict__ Ain, const bf16* __restrict__ Bt, const float* __restrict__ bias,
    float* __restrict__ out, const int* __restrict__ perm,
    const int* __restrict__ tileE, const int* __restrict__ tileR,
    const int* __restrict__ off, const int* __restrict__ ntp)
{
    GEMM_PROLOGUE(HD)
    const bf16* Ab = Ain + (size_t)(base + row0) * HD;
    const bf16* Bb = Bt  + ((size_t)e * OD + n0) * HD;
    GEMM_KLOOP(HD)
    for (int i = 0; i < 4; i++) {
        int rb = wm * 64 + i * 16 + qd * 4;
        for (int r = 0; r < 4; r++) {
            int m = rb + r;
            if (m >= valid) continue;
            int tok = perm[base + row0 + m];
            size_t orow = (size_t)tok * OD;
            for (int j = 0; j < 4; j++) {
                int n = n0 + wn * 64 + j * 16 + lr;
                out[orow + n] = acc[i][j][r] + bias[e * OD + n];
            }
        }
    }
}

// ---------------- launch ----------------
extern "C" void kernel_launch(void* const* d_in, const int* in_sizes, int n_in,
                              void* d_out, int out_size, void* d_ws, size_t ws_size,
                              hipStream_t stream) {
    const float* x   = (const float*)d_in[0];
    const int*   sel = (const int*)d_in[1];
    const float* Wg  = (const float*)d_in[2];
    const float* bg  = (const float*)d_in[3];
    const float* Wu  = (const float*)d_in[4];
    const float* bu  = (const float*)d_in[5];
    const float* W1  = (const float*)d_in[6];
    const float* b1  = (const float*)d_in[7];
    const float* W2  = (const float*)d_in[8];
    const float* b2  = (const float*)d_in[9];
    float* out = (float*)d_out;

    char* ws = (char*)d_ws;
    int* cnt   = (int*)(ws + O_CNT);
    int* cur   = (int*)(ws + O_CUR);
    int* off   = (int*)(ws + O_OFF);
    int* nt    = (int*)(ws + O_NT);
    int* tileE = (int*)(ws + O_TE);
    int* tileR = (int*)(ws + O_TR);
    int* perm  = (int*)(ws + O_PERM);
    bf16* Xp   = (bf16*)(ws + O_XP);
    bf16* Wgt  = (bf16*)(ws + O_WG);
    bf16* Wut  = (bf16*)(ws + O_WU);
    bf16* W1t  = (bf16*)(ws + O_W1);
    bf16* W2t  = (bf16*)(ws + O_W2);
    bf16* Hbuf = (bf16*)(ws + O_H);
    bf16* Gbuf = (bf16*)(ws + O_H2);   // G during SwiGLU phase
    bf16* H2   = (bf16*)(ws + O_H2);   // overwritten by gemm2 after G is dead

    hipMemsetAsync(ws, 0, 256, stream);

    k_hist   <<<NTOK / 256, 256, 0, stream>>>(sel, cnt);
    k_plan   <<<1, 64, 0, stream>>>(cnt, off, tileE, tileR, nt);
    k_scatter<<<NTOK / 256, 256, 0, stream>>>(sel, off, cur, perm);
    k_gather <<<NTOK * 64 / 256, 256, 0, stream>>>(x, perm, Xp);

    k_transpose<<<dim3(FD / 64, HD / 64, NEXP), 256, 0, stream>>>(Wg, Wgt, FD, HD);
    k_transpose<<<dim3(FD / 64, HD / 64, NEXP), 256, 0, stream>>>(Wu, Wut, FD, HD);
    k_transpose<<<dim3(HD / 64, HD / 64, NEXP), 256, 0, stream>>>(W1, W1t, HD, HD);
    k_transpose<<<dim3(HD / 64, OD / 64, NEXP), 256, 0, stream>>>(W2, W2t, HD, OD);

    k_gate <<<dim3(MAX_TILES, HD / BN), 256, 0, stream>>>(Xp, Wgt, bg, Gbuf,
                                                          tileE, tileR, off, nt);
    k_up   <<<dim3(MAX_TILES, HD / BN), 256, 0, stream>>>(Xp, Wut, bu, Gbuf, Hbuf,
                                                          tileE, tileR, off, nt);
    k_gemm2<<<dim3(MAX_TILES, HD / BN), 256, 0, stream>>>(Hbuf, W1t, b1, H2,
                                                          tileE, tileR, off, nt);
    k_gemm3<<<dim3(MAX_TILES, OD / BN), 256, 0, stream>>>(H2, W2t, b2, out, perm,
                                                          tileE, tileR, off, nt);
}

// Round 7
// 364.393 us; speedup vs baseline: 1.9580x; 1.0949x over previous
//
#include <hip/hip_runtime.h>
#include <hip/hip_bf16.h>
#include <cstdint>
#include <cstddef>

// Problem constants
#define NTOK 32768   // P*N*K token-copies
#define FD   256     // input feature dim
#define HD   1024    // hidden dim
#define OD   256     // output dim
#define NEXP 8

// GEMM tiling
#define BM 128
#define BN 128
#define BK 32
#define MAX_TILES 272

typedef __bf16 bf16;
typedef __bf16 bf16x8 __attribute__((ext_vector_type(8)));
typedef __bf16 bf16x4 __attribute__((ext_vector_type(4)));
typedef float  f32x4  __attribute__((ext_vector_type(4)));

// async global->LDS, 16 B per lane. LDS dst MUST be wave-uniform base + lane*16.
__device__ __forceinline__ void cp16(const void* g, void* l) {
    __builtin_amdgcn_global_load_lds(
        (const __attribute__((address_space(1))) void*)g,
        (__attribute__((address_space(3))) void*)l, 16, 0, 0);
}

// ---- workspace layout (bytes) ----
static const size_t O_CNT  = 0;          // int[8]
static const size_t O_CUR  = 64;         // int[8]
static const size_t O_OFF  = 128;        // int[9]
static const size_t O_NT   = 192;        // int[1]
static const size_t O_TE   = 1024;       // int[512]
static const size_t O_TR   = 3072;       // int[512]
static const size_t O_PERM = 5120;       // int[NTOK]
static const size_t O_XP   = 136192;     // bf16 [NTOK][FD]    (16 MB)
static const size_t O_WG   = 16913408;   // bf16 [E][HD][FD]   (4 MB)
static const size_t O_WU   = 21107712;   // bf16 [E][HD][FD]   (4 MB)
static const size_t O_W1   = 25302016;   // bf16 [E][HD][HD]   (16 MB)
static const size_t O_W2   = 42079232;   // bf16 [E][OD][HD]   (4 MB)
static const size_t O_H    = 46273536;   // bf16 [NTOK][HD]    (64 MB) Hbuf
static const size_t O_H2   = 113382400;  // bf16 [NTOK][HD]    (64 MB) H2

// ---------------- routing ----------------
// Two-level histogram: LDS per-block counts, then 8 global atomics per block.
__global__ void k_hist(const int* __restrict__ sel, int* __restrict__ cnt) {
    __shared__ int lcnt[NEXP];
    if (threadIdx.x < NEXP) lcnt[threadIdx.x] = 0;
    __syncthreads();
    int t = blockIdx.x * 256 + threadIdx.x;   // NTOK % 256 == 0
    atomicAdd(&lcnt[sel[t]], 1);
    __syncthreads();
    if (threadIdx.x < NEXP) atomicAdd(&cnt[threadIdx.x], lcnt[threadIdx.x]);
}

__global__ void k_plan(const int* __restrict__ cnt, int* __restrict__ off,
                       int* __restrict__ tileE, int* __restrict__ tileR,
                       int* __restrict__ nt) {
    if (threadIdx.x == 0 && blockIdx.x == 0) {
        int o = 0;
        for (int e = 0; e < NEXP; e++) { off[e] = o; o += cnt[e]; }
        off[NEXP] = o;
        int n = 0;
        for (int e = 0; e < NEXP; e++) {
            int c = cnt[e];
            int nte = (c + BM - 1) / BM;
            for (int r = 0; r < nte; r++) { tileE[n] = e; tileR[n] = r; n++; }
        }
        *nt = n;
    }
}

__global__ void k_scatter(const int* __restrict__ sel, const int* __restrict__ off,
                          int* __restrict__ cur, int* __restrict__ perm) {
    __shared__ int lcnt[NEXP];
    __shared__ int lbase[NEXP];
    if (threadIdx.x < NEXP) lcnt[threadIdx.x] = 0;
    __syncthreads();
    int t = blockIdx.x * 256 + threadIdx.x;
    int e = sel[t];
    int rank = atomicAdd(&lcnt[e], 1);
    __syncthreads();
    if (threadIdx.x < NEXP)
        lbase[threadIdx.x] = atomicAdd(&cur[threadIdx.x], lcnt[threadIdx.x]);
    __syncthreads();
    perm[off[e] + lbase[e] + rank] = t;
}

__global__ void k_gather(const float* __restrict__ x, const int* __restrict__ perm,
                         bf16* __restrict__ Xp) {
    int gid = blockIdx.x * 256 + threadIdx.x;
    int pos = gid >> 6;
    int c   = gid & 63;
    int tok = perm[pos];
    float4 v = ((const float4*)x)[(size_t)tok * 64 + c];
    bf16x4 o;
    o.x = (bf16)v.x; o.y = (bf16)v.y; o.z = (bf16)v.z; o.w = (bf16)v.w;
    *(bf16x4*)&Xp[(size_t)pos * FD + c * 4] = o;
}

// All 4 weight transposes in ONE launch. W [E][K][N] fp32 -> Wt [E][N][K] bf16.
// Per-expert tile counts: Wg 4x16=64, Wu 64, W1 16x16=256, W2 16x4=64 -> 448.
#define TPE 448
__global__ void k_transpose_all(const float* __restrict__ Wg, bf16* __restrict__ Wgt,
                                const float* __restrict__ Wu, bf16* __restrict__ Wut,
                                const float* __restrict__ W1, bf16* __restrict__ W1t,
                                const float* __restrict__ W2, bf16* __restrict__ W2t) {
    __shared__ float tile[64][65];
    int b  = blockIdx.x;
    int e  = b / TPE;
    int tt = b % TPE;
    const float* Ws; bf16* Wd; int K, N;
    if (tt < 64)       { Ws = Wg; Wd = Wgt; K = FD; N = HD; }
    else if (tt < 128) { Ws = Wu; Wd = Wut; K = FD; N = HD; tt -= 64; }
    else if (tt < 384) { Ws = W1; Wd = W1t; K = HD; N = HD; tt -= 128; }
    else               { Ws = W2; Wd = W2t; K = HD; N = OD; tt -= 384; }
    int nk = K / 64;
    int k0 = (tt % nk) * 64, n0 = (tt / nk) * 64;
    Ws += (size_t)e * K * N;
    Wd += (size_t)e * K * N;
    int t = threadIdx.x;
    for (int q = 0; q < 4; q++) {
        int lin = t + q * 256;
        int r = lin >> 4, c4 = (lin & 15) * 4;
        float4 v = *(const float4*)&Ws[(size_t)(k0 + r) * N + n0 + c4];
        tile[r][c4] = v.x; tile[r][c4+1] = v.y; tile[r][c4+2] = v.z; tile[r][c4+3] = v.w;
    }
    __syncthreads();
    for (int q = 0; q < 2; q++) {   // 64 n * 8 chunks = 512 items
        int lin = t + q * 256;
        int n = lin >> 3, k8 = (lin & 7) * 8;
        bf16x8 o;
        for (int i = 0; i < 8; i++) o[i] = (bf16)tile[k8 + i][n];
        *(bf16x8*)&Wd[(size_t)(n0 + n) * K + k0 + k8] = o;
    }
}

// ---------------- GEMM kernels ----------------
// MFMA 16x16x32 bf16 layouts (HW-verified):
//   A-frag: lane holds A[m=lane&15][k=(lane>>4)*8+j]
//   B-frag: lane holds B[k=(lane>>4)*8+j][n=lane&15]
//   C/D   : lane,reg r -> C[(lane>>4)*4+r][lane&15]
// LDS: unpadded [rows][BK], XOR chunk swizzle: slot s holds chunk s^((row>>1)&3);
//   read slot = qd^((row>>1)&3) -> max 2-way bank aliasing (free).
// __launch_bounds__(256,4): 64 AGPR + ~60 VGPR = ~124 <= 128 -> 4 blocks/CU.

#define GEMM_PROLOGUE(KDIM)                                                    \
    if (blockIdx.x >= *ntp) return;                                            \
    __shared__ bf16 As[BM * BK];                                               \
    __shared__ bf16 Bs[BN * BK];                                               \
    int e    = tileE[blockIdx.x];                                              \
    int row0 = tileR[blockIdx.x] * BM;                                         \
    int base = off[e];                                                         \
    int valid = off[e + 1] - base - row0; if (valid > BM) valid = BM;          \
    int n0 = blockIdx.y * BN;                                                  \
    int tid = threadIdx.x;                                                     \
    int lane = tid & 63, wv = tid >> 6;                                        \
    int wm = wv & 1, wn = wv >> 1;                                             \
    int lr = lane & 15, qd = lane >> 4;                                        \
    f32x4 acc[4][4] = {};

#define GEMM_KLOOP(KDIM)                                                       \
    for (int k0 = 0; k0 < (KDIM); k0 += BK) {                                  \
        for (int s = 0; s < 2; s++) {                                          \
            int ci = tid + s * 256;                                            \
            int m  = ci >> 2;                                                  \
            int jg = (ci & 3) ^ ((m >> 1) & 3);                                \
            int mc = m < valid ? m : valid - 1;                                \
            cp16(Ab + (size_t)mc * (KDIM) + k0 + jg * 8, &As[ci * 8]);         \
            cp16(Bb + (size_t)m  * (KDIM) + k0 + jg * 8, &Bs[ci * 8]);         \
        }                                                                      \
        __syncthreads();                                                       \
        bf16x8 af[4], bfr[4];                                                  \
        for (int i = 0; i < 4; i++) {                                          \
            int row = wm * 64 + i * 16 + lr;                                   \
            int sl  = qd ^ ((row >> 1) & 3);                                   \
            af[i] = *(const bf16x8*)&As[row * BK + sl * 8];                    \
        }                                                                      \
        for (int j = 0; j < 4; j++) {                                          \
            int row = wn * 64 + j * 16 + lr;                                   \
            int sl  = qd ^ ((row >> 1) & 3);                                   \
            bfr[j] = *(const bf16x8*)&Bs[row * BK + sl * 8];                   \
        }                                                                      \
        for (int i = 0; i < 4; i++)                                            \
            for (int j = 0; j < 4; j++)                                        \
                acc[i][j] = __builtin_amdgcn_mfma_f32_16x16x32_bf16(           \
                    af[i], bfr[j], acc[i][j], 0, 0, 0);                        \
        __syncthreads();                                                       \
    }

// Fused SwiGLU GEMM: Hbuf = silu(Xp@Wg+bg) * (Xp@Wu+bu).
// BM=128 x BN=64 per block (wave: 64 rows x 32 cols, 2 j-frags each of g,u).
// acc: 4i x 2j x 2 = 16 f32x4 = 64 AGPR -> same budget as plain GEMM.
__global__ __launch_bounds__(256, 4) void k_swiglu(
    const bf16* __restrict__ Xp, const bf16* __restrict__ Wgt, const bf16* __restrict__ Wut,
    const float* __restrict__ bg, const float* __restrict__ bu, bf16* __restrict__ Hbuf,
    const int* __restrict__ tileE, const int* __restrict__ tileR,
    const int* __restrict__ off, const int* __restrict__ ntp)
{
    if (blockIdx.x >= *ntp) return;
    __shared__ bf16 As [BM * BK];        // 8 KB
    __shared__ bf16 Bgs[64 * BK];        // 4 KB
    __shared__ bf16 Bus[64 * BK];        // 4 KB
    int e    = tileE[blockIdx.x];
    int row0 = tileR[blockIdx.x] * BM;
    int base = off[e];
    int valid = off[e + 1] - base - row0; if (valid > BM) valid = BM;
    int n0 = blockIdx.y * 64;
    int tid = threadIdx.x;
    int lane = tid & 63, wv = tid >> 6;
    int wm = wv & 1, wn = wv >> 1;
    int lr = lane & 15, qd = lane >> 4;

    f32x4 accg[4][2] = {};
    f32x4 accu[4][2] = {};
    const bf16* Ab  = Xp  + (size_t)(base + row0) * FD;
    const bf16* Bgb = Wgt + ((size_t)e * HD + n0) * FD;
    const bf16* Bub = Wut + ((size_t)e * HD + n0) * FD;

    for (int k0 = 0; k0 < FD; k0 += BK) {
        for (int s = 0; s < 2; s++) {                  // A: 512 chunks
            int ci = tid + s * 256;
            int m  = ci >> 2;
            int jg = (ci & 3) ^ ((m >> 1) & 3);
            int mc = m < valid ? m : valid - 1;
            cp16(Ab + (size_t)mc * FD + k0 + jg * 8, &As[ci * 8]);
        }
        {                                              // Bg,Bu: 256 chunks each
            int ci = tid;
            int m  = ci >> 2;
            int jg = (ci & 3) ^ ((m >> 1) & 3);
            cp16(Bgb + (size_t)m * FD + k0 + jg * 8, &Bgs[ci * 8]);
            cp16(Bub + (size_t)m * FD + k0 + jg * 8, &Bus[ci * 8]);
        }
        __syncthreads();
        bf16x8 af[4], bgf[2], buf[2];
        for (int i = 0; i < 4; i++) {
            int row = wm * 64 + i * 16 + lr;
            int sl  = qd ^ ((row >> 1) & 3);
            af[i] = *(const bf16x8*)&As[row * BK + sl * 8];
        }
        for (int j = 0; j < 2; j++) {
            int row = wn * 32 + j * 16 + lr;
            int sl  = qd ^ ((row >> 1) & 3);
            bgf[j] = *(const bf16x8*)&Bgs[row * BK + sl * 8];
            buf[j] = *(const bf16x8*)&Bus[row * BK + sl * 8];
        }
        for (int i = 0; i < 4; i++)
            for (int j = 0; j < 2; j++) {
                accg[i][j] = __builtin_amdgcn_mfma_f32_16x16x32_bf16(af[i], bgf[j], accg[i][j], 0, 0, 0);
                accu[i][j] = __builtin_amdgcn_mfma_f32_16x16x32_bf16(af[i], buf[j], accu[i][j], 0, 0, 0);
            }
        __syncthreads();
    }
    for (int i = 0; i < 4; i++) {
        int rb = wm * 64 + i * 16 + qd * 4;
        for (int r = 0; r < 4; r++) {
            int m = rb + r;
            if (m >= valid) continue;
            size_t orow = (size_t)(base + row0 + m) * HD;
            for (int j = 0; j < 2; j++) {
                int n = n0 + wn * 32 + j * 16 + lr;
                float g = accg[i][j][r] + bg[e * HD + n];
                float u = accu[i][j][r] + bu[e * HD + n];
                float h = g * u / (1.f + __expf(-g));   // silu(g)*u
                Hbuf[orow + n] = (bf16)h;
            }
        }
    }
}

// gemm2: H2 = relu(Hbuf@W1 + b1)
__global__ __launch_bounds__(256, 4) void k_gemm2(
    const bf16* __restrict__ Ain, const bf16* __restrict__ Bt, const float* __restrict__ bias,
    bf16* __restrict__ Out,
    const int* __restrict__ tileE, const int* __restrict__ tileR,
    const int* __restrict__ off, const int* __restrict__ ntp)
{
    GEMM_PROLOGUE(HD)
    const bf16* Ab = Ain + (size_t)(base + row0) * HD;
    const bf16* Bb = Bt  + ((size_t)e * HD + n0) * HD;
    GEMM_KLOOP(HD)
    for (int i = 0; i < 4; i++) {
        int rb = wm * 64 + i * 16 + qd * 4;
        for (int r = 0; r < 4; r++) {
            int m = rb + r;
            if (m >= valid) continue;
            size_t orow = (size_t)(base + row0 + m) * HD;
            for (int j = 0; j < 4; j++) {
                int n = n0 + wn * 64 + j * 16 + lr;
                float v = acc[i][j][r] + bias[e * HD + n];
                Out[orow + n] = (bf16)(v > 0.f ? v : 0.f);
            }
        }
    }
}

// gemm3: out[perm] = H2@W2 + b2 (fp32 scatter)
__global__ __launch_bounds__(256, 4) void k_gemm3(
    const bf16* __restrict__ Ain, const bf16* __restrict__ Bt, const float* __restrict__ bias,
    float* __restrict__ out, const int* __restrict__ perm,
    const int* __restrict__ tileE, const int* __restrict__ tileR,
    const int* __restrict__ off, const int* __restrict__ ntp)
{
    GEMM_PROLOGUE(HD)
    const bf16* Ab = Ain + (size_t)(base + row0) * HD;
    const bf16* Bb = Bt  + ((size_t)e * OD + n0) * HD;
    GEMM_KLOOP(HD)
    for (int i = 0; i < 4; i++) {
        int rb = wm * 64 + i * 16 + qd * 4;
        for (int r = 0; r < 4; r++) {
            int m = rb + r;
            if (m >= valid) continue;
            int tok = perm[base + row0 + m];
            size_t orow = (size_t)tok * OD;
            for (int j = 0; j < 4; j++) {
                int n = n0 + wn * 64 + j * 16 + lr;
                out[orow + n] = acc[i][j][r] + bias[e * OD + n];
            }
        }
    }
}

// ---------------- launch ----------------
extern "C" void kernel_launch(void* const* d_in, const int* in_sizes, int n_in,
                              void* d_out, int out_size, void* d_ws, size_t ws_size,
                              hipStream_t stream) {
    const float* x   = (const float*)d_in[0];
    const int*   sel = (const int*)d_in[1];
    const float* Wg  = (const float*)d_in[2];
    const float* bg  = (const float*)d_in[3];
    const float* Wu  = (const float*)d_in[4];
    const float* bu  = (const float*)d_in[5];
    const float* W1  = (const float*)d_in[6];
    const float* b1  = (const float*)d_in[7];
    const float* W2  = (const float*)d_in[8];
    const float* b2  = (const float*)d_in[9];
    float* out = (float*)d_out;

    char* ws = (char*)d_ws;
    int* cnt   = (int*)(ws + O_CNT);
    int* cur   = (int*)(ws + O_CUR);
    int* off   = (int*)(ws + O_OFF);
    int* nt    = (int*)(ws + O_NT);
    int* tileE = (int*)(ws + O_TE);
    int* tileR = (int*)(ws + O_TR);
    int* perm  = (int*)(ws + O_PERM);
    bf16* Xp   = (bf16*)(ws + O_XP);
    bf16* Wgt  = (bf16*)(ws + O_WG);
    bf16* Wut  = (bf16*)(ws + O_WU);
    bf16* W1t  = (bf16*)(ws + O_W1);
    bf16* W2t  = (bf16*)(ws + O_W2);
    bf16* Hbuf = (bf16*)(ws + O_H);
    bf16* H2   = (bf16*)(ws + O_H2);

    hipMemsetAsync(ws, 0, 256, stream);

    k_hist   <<<NTOK / 256, 256, 0, stream>>>(sel, cnt);
    k_plan   <<<1, 64, 0, stream>>>(cnt, off, tileE, tileR, nt);
    k_scatter<<<NTOK / 256, 256, 0, stream>>>(sel, off, cur, perm);
    k_gather <<<NTOK * 64 / 256, 256, 0, stream>>>(x, perm, Xp);

    k_transpose_all<<<NEXP * TPE, 256, 0, stream>>>(Wg, Wgt, Wu, Wut, W1, W1t, W2, W2t);

    k_swiglu<<<dim3(MAX_TILES, HD / 64), 256, 0, stream>>>(Xp, Wgt, Wut, bg, bu, Hbuf,
                                                           tileE, tileR, off, nt);
    k_gemm2 <<<dim3(MAX_TILES, HD / BN), 256, 0, stream>>>(Hbuf, W1t, b1, H2,
                                                           tileE, tileR, off, nt);
    k_gemm3 <<<dim3(MAX_TILES, OD / BN), 256, 0, stream>>>(H2, W2t, b2, out, perm,
                                                           tileE, tileR, off, nt);
}

// Round 8
// 340.619 us; speedup vs baseline: 2.0946x; 1.0698x over previous
//
#include <hip/hip_runtime.h>
#include <hip/hip_bf16.h>
#include <cstdint>
#include <cstddef>

// Problem constants
#define NTOK 32768   // P*N*K token-copies
#define FD   256     // input feature dim
#define HD   1024    // hidden dim
#define OD   256     // output dim
#define NEXP 8

// GEMM tiling
#define BM 128
#define BN 128
#define BK 64        // 32 MFMA per barrier (was 16) -> double drain coverage
#define MAXRT 34     // ceil(272 row-tiles / 8 xcds) ... max row-tiles = 272? no: 34*8=272
#define RT8 34       // Rhi range: ceil(MAX row-tiles / 8) ; max tiles = 272 -> 34

typedef __bf16 bf16;
typedef __bf16 bf16x8 __attribute__((ext_vector_type(8)));
typedef __bf16 bf16x4 __attribute__((ext_vector_type(4)));
typedef float  f32x4  __attribute__((ext_vector_type(4)));

// async global->LDS, 16 B per lane. LDS dst MUST be wave-uniform base + lane*16.
__device__ __forceinline__ void cp16(const void* g, void* l) {
    __builtin_amdgcn_global_load_lds(
        (const __attribute__((address_space(1))) void*)g,
        (__attribute__((address_space(3))) void*)l, 16, 0, 0);
}

// ---- workspace layout (bytes) ----
static const size_t O_CNT  = 0;          // int[8]
static const size_t O_CUR  = 64;         // int[8]
static const size_t O_OFF  = 128;        // int[9]
static const size_t O_NT   = 192;        // int[1]
static const size_t O_TE   = 1024;       // int[512]
static const size_t O_TR   = 3072;       // int[512]
static const size_t O_PERM = 5120;       // int[NTOK]
static const size_t O_XP   = 136192;     // bf16 [NTOK][FD]    (16 MB)
static const size_t O_WG   = 16913408;   // bf16 [E][HD][FD]   (4 MB)
static const size_t O_WU   = 21107712;   // bf16 [E][HD][FD]   (4 MB)
static const size_t O_W1   = 25302016;   // bf16 [E][HD][HD]   (16 MB)
static const size_t O_W2   = 42079232;   // bf16 [E][OD][HD]   (4 MB)
static const size_t O_H    = 46273536;   // bf16 [NTOK][HD]    (64 MB) Hbuf
static const size_t O_H2   = 113382400;  // bf16 [NTOK][HD]    (64 MB) H2

// ---------------- routing ----------------
__global__ void k_hist(const int* __restrict__ sel, int* __restrict__ cnt) {
    __shared__ int lcnt[NEXP];
    if (threadIdx.x < NEXP) lcnt[threadIdx.x] = 0;
    __syncthreads();
    int t = blockIdx.x * 256 + threadIdx.x;   // NTOK % 256 == 0
    atomicAdd(&lcnt[sel[t]], 1);
    __syncthreads();
    if (threadIdx.x < NEXP) atomicAdd(&cnt[threadIdx.x], lcnt[threadIdx.x]);
}

__global__ void k_plan(const int* __restrict__ cnt, int* __restrict__ off,
                       int* __restrict__ tileE, int* __restrict__ tileR,
                       int* __restrict__ nt) {
    if (threadIdx.x == 0 && blockIdx.x == 0) {
        int o = 0;
        for (int e = 0; e < NEXP; e++) { off[e] = o; o += cnt[e]; }
        off[NEXP] = o;
        int n = 0;
        for (int e = 0; e < NEXP; e++) {
            int c = cnt[e];
            int nte = (c + BM - 1) / BM;
            for (int r = 0; r < nte; r++) { tileE[n] = e; tileR[n] = r; n++; }
        }
        *nt = n;
    }
}

__global__ void k_scatter(const int* __restrict__ sel, const int* __restrict__ off,
                          int* __restrict__ cur, int* __restrict__ perm) {
    __shared__ int lcnt[NEXP];
    __shared__ int lbase[NEXP];
    if (threadIdx.x < NEXP) lcnt[threadIdx.x] = 0;
    __syncthreads();
    int t = blockIdx.x * 256 + threadIdx.x;
    int e = sel[t];
    int rank = atomicAdd(&lcnt[e], 1);
    __syncthreads();
    if (threadIdx.x < NEXP)
        lbase[threadIdx.x] = atomicAdd(&cur[threadIdx.x], lcnt[threadIdx.x]);
    __syncthreads();
    perm[off[e] + lbase[e] + rank] = t;
}

__global__ void k_gather(const float* __restrict__ x, const int* __restrict__ perm,
                         bf16* __restrict__ Xp) {
    int gid = blockIdx.x * 256 + threadIdx.x;
    int pos = gid >> 6;
    int c   = gid & 63;
    int tok = perm[pos];
    float4 v = ((const float4*)x)[(size_t)tok * 64 + c];
    bf16x4 o;
    o.x = (bf16)v.x; o.y = (bf16)v.y; o.z = (bf16)v.z; o.w = (bf16)v.w;
    *(bf16x4*)&Xp[(size_t)pos * FD + c * 4] = o;
}

// All 4 weight transposes in ONE launch. W [E][K][N] fp32 -> Wt [E][N][K] bf16.
#define TPE 448
__global__ void k_transpose_all(const float* __restrict__ Wg, bf16* __restrict__ Wgt,
                                const float* __restrict__ Wu, bf16* __restrict__ Wut,
                                const float* __restrict__ W1, bf16* __restrict__ W1t,
                                const float* __restrict__ W2, bf16* __restrict__ W2t) {
    __shared__ float tile[64][65];
    int b  = blockIdx.x;
    int e  = b / TPE;
    int tt = b % TPE;
    const float* Ws; bf16* Wd; int K, N;
    if (tt < 64)       { Ws = Wg; Wd = Wgt; K = FD; N = HD; }
    else if (tt < 128) { Ws = Wu; Wd = Wut; K = FD; N = HD; tt -= 64; }
    else if (tt < 384) { Ws = W1; Wd = W1t; K = HD; N = HD; tt -= 128; }
    else               { Ws = W2; Wd = W2t; K = HD; N = OD; tt -= 384; }
    int nk = K / 64;
    int k0 = (tt % nk) * 64, n0 = (tt / nk) * 64;
    Ws += (size_t)e * K * N;
    Wd += (size_t)e * K * N;
    int t = threadIdx.x;
    for (int q = 0; q < 4; q++) {
        int lin = t + q * 256;
        int r = lin >> 4, c4 = (lin & 15) * 4;
        float4 v = *(const float4*)&Ws[(size_t)(k0 + r) * N + n0 + c4];
        tile[r][c4] = v.x; tile[r][c4+1] = v.y; tile[r][c4+2] = v.z; tile[r][c4+3] = v.w;
    }
    __syncthreads();
    for (int q = 0; q < 2; q++) {   // 64 n * 8 chunks = 512 items
        int lin = t + q * 256;
        int n = lin >> 3, k8 = (lin & 7) * 8;
        bf16x8 o;
        for (int i = 0; i < 8; i++) o[i] = (bf16)tile[k8 + i][n];
        *(bf16x8*)&Wd[(size_t)(n0 + n) * K + k0 + k8] = o;
    }
}

// ---------------- GEMM kernels ----------------
// MFMA 16x16x32 bf16 (HW-verified layouts). BK=64: 2 k-steps per barrier.
// LDS: unpadded [rows][64], XOR chunk swizzle over 8 chunks/row:
//   slot s holds global chunk s ^ (row&7); read slot (ks*4+qd)^(row&7)
//   -> 8 start-banks x b128(4 banks) covers all 32 banks, 2 lanes each (free).
// XCD swizzle: 1D grid, xcd=L&7, ny=(L>>3)%NTY, R=((L>>3)/NTY)*8+xcd.
//   With round-robin wgid->XCD, all n-tiles of a row-tile are consecutive on
//   one XCD -> A staged from that XCD's L2 after first touch (speed-only).

#define DECODE_TILE(NTY, BNE)                                                  \
    int L = blockIdx.x;                                                        \
    int xcd = L & 7; int tq = L >> 3;                                          \
    int ny  = tq % (NTY); int Rhi = tq / (NTY);                                \
    int R   = Rhi * 8 + xcd;                                                   \
    if (R >= *ntp) return;                                                     \
    int e    = tileE[R];                                                       \
    int row0 = tileR[R] * BM;                                                  \
    int base = off[e];                                                         \
    int valid = off[e + 1] - base - row0; if (valid > BM) valid = BM;          \
    int n0 = ny * (BNE);                                                       \
    int tid = threadIdx.x;                                                     \
    int lane = tid & 63, wv = tid >> 6;                                        \
    int wm = wv & 1, wn = wv >> 1;                                             \
    int lr = lane & 15, qd = lane >> 4;

#define GEMM_KLOOP(KDIM)                                                       \
    for (int k0 = 0; k0 < (KDIM); k0 += BK) {                                  \
        for (int s = 0; s < 4; s++) {                                          \
            int ci = tid + s * 256;                                            \
            int row = ci >> 3;                                                 \
            int jg  = (ci & 7) ^ (row & 7);                                    \
            int mc  = row < valid ? row : valid - 1;                           \
            cp16(Ab + (size_t)mc  * (KDIM) + k0 + jg * 8, &As[ci * 8]);        \
            cp16(Bb + (size_t)row * (KDIM) + k0 + jg * 8, &Bs[ci * 8]);        \
        }                                                                      \
        __syncthreads();                                                       \
        for (int ks = 0; ks < 2; ks++) {                                       \
            bf16x8 af[4], bfr[4];                                              \
            for (int i = 0; i < 4; i++) {                                      \
                int row = wm * 64 + i * 16 + lr;                               \
                int sl  = (ks * 4 + qd) ^ (row & 7);                           \
                af[i] = *(const bf16x8*)&As[row * BK + sl * 8];                \
            }                                                                  \
            for (int j = 0; j < 4; j++) {                                      \
                int row = wn * 64 + j * 16 + lr;                               \
                int sl  = (ks * 4 + qd) ^ (row & 7);                           \
                bfr[j] = *(const bf16x8*)&Bs[row * BK + sl * 8];               \
            }                                                                  \
            for (int i = 0; i < 4; i++)                                        \
                for (int j = 0; j < 4; j++)                                    \
                    acc[i][j] = __builtin_amdgcn_mfma_f32_16x16x32_bf16(       \
                        af[i], bfr[j], acc[i][j], 0, 0, 0);                    \
        }                                                                      \
        __syncthreads();                                                       \
    }

// Fused SwiGLU: Hbuf = silu(Xp@Wg+bg) * (Xp@Wu+bu). BM=128 x BN=64, K=FD=256.
__global__ __launch_bounds__(256, 3) void k_swiglu(
    const bf16* __restrict__ Xp, const bf16* __restrict__ Wgt, const bf16* __restrict__ Wut,
    const float* __restrict__ bg, const float* __restrict__ bu, bf16* __restrict__ Hbuf,
    const int* __restrict__ tileE, const int* __restrict__ tileR,
    const int* __restrict__ off, const int* __restrict__ ntp)
{
    __shared__ bf16 As [BM * BK];        // 16 KB
    __shared__ bf16 Bgs[64 * BK];        // 8 KB
    __shared__ bf16 Bus[64 * BK];        // 8 KB
    DECODE_TILE(16, 64)

    f32x4 accg[4][2] = {};
    f32x4 accu[4][2] = {};
    const bf16* Ab  = Xp  + (size_t)(base + row0) * FD;
    const bf16* Bgb = Wgt + ((size_t)e * HD + n0) * FD;
    const bf16* Bub = Wut + ((size_t)e * HD + n0) * FD;

    for (int k0 = 0; k0 < FD; k0 += BK) {
        for (int s = 0; s < 4; s++) {                  // A: 1024 chunks
            int ci = tid + s * 256;
            int row = ci >> 3;
            int jg  = (ci & 7) ^ (row & 7);
            int mc  = row < valid ? row : valid - 1;
            cp16(Ab + (size_t)mc * FD + k0 + jg * 8, &As[ci * 8]);
        }
        for (int s = 0; s < 2; s++) {                  // Bg,Bu: 512 chunks each
            int ci = tid + s * 256;
            int row = ci >> 3;
            int jg  = (ci & 7) ^ (row & 7);
            cp16(Bgb + (size_t)row * FD + k0 + jg * 8, &Bgs[ci * 8]);
            cp16(Bub + (size_t)row * FD + k0 + jg * 8, &Bus[ci * 8]);
        }
        __syncthreads();
        for (int ks = 0; ks < 2; ks++) {
            bf16x8 af[4], bgf[2], buf[2];
            for (int i = 0; i < 4; i++) {
                int row = wm * 64 + i * 16 + lr;
                int sl  = (ks * 4 + qd) ^ (row & 7);
                af[i] = *(const bf16x8*)&As[row * BK + sl * 8];
            }
            for (int j = 0; j < 2; j++) {
                int row = wn * 32 + j * 16 + lr;
                int sl  = (ks * 4 + qd) ^ (row & 7);
                bgf[j] = *(const bf16x8*)&Bgs[row * BK + sl * 8];
                buf[j] = *(const bf16x8*)&Bus[row * BK + sl * 8];
            }
            for (int i = 0; i < 4; i++)
                for (int j = 0; j < 2; j++) {
                    accg[i][j] = __builtin_amdgcn_mfma_f32_16x16x32_bf16(af[i], bgf[j], accg[i][j], 0, 0, 0);
                    accu[i][j] = __builtin_amdgcn_mfma_f32_16x16x32_bf16(af[i], buf[j], accu[i][j], 0, 0, 0);
                }
        }
        __syncthreads();
    }
    for (int i = 0; i < 4; i++) {
        int rb = wm * 64 + i * 16 + qd * 4;
        for (int r = 0; r < 4; r++) {
            int m = rb + r;
            if (m >= valid) continue;
            size_t orow = (size_t)(base + row0 + m) * HD;
            for (int j = 0; j < 2; j++) {
                int n = n0 + wn * 32 + j * 16 + lr;
                float g = accg[i][j][r] + bg[e * HD + n];
                float u = accu[i][j][r] + bu[e * HD + n];
                float h = g * u / (1.f + __expf(-g));   // silu(g)*u
                Hbuf[orow + n] = (bf16)h;
            }
        }
    }
}

// gemm2: H2 = relu(Hbuf@W1 + b1). K=HD, NTY=8.
__global__ __launch_bounds__(256, 3) void k_gemm2(
    const bf16* __restrict__ Ain, const bf16* __restrict__ Bt, const float* __restrict__ bias,
    bf16* __restrict__ Out,
    const int* __restrict__ tileE, const int* __restrict__ tileR,
    const int* __restrict__ off, const int* __restrict__ ntp)
{
    __shared__ bf16 As[BM * BK];   // 16 KB
    __shared__ bf16 Bs[BN * BK];   // 16 KB
    DECODE_TILE(8, BN)
    f32x4 acc[4][4] = {};
    const bf16* Ab = Ain + (size_t)(base + row0) * HD;
    const bf16* Bb = Bt  + ((size_t)e * HD + n0) * HD;
    GEMM_KLOOP(HD)
    for (int i = 0; i < 4; i++) {
        int rb = wm * 64 + i * 16 + qd * 4;
        for (int r = 0; r < 4; r++) {
            int m = rb + r;
            if (m >= valid) continue;
            size_t orow = (size_t)(base + row0 + m) * HD;
            for (int j = 0; j < 4; j++) {
                int n = n0 + wn * 64 + j * 16 + lr;
                float v = acc[i][j][r] + bias[e * HD + n];
                Out[orow + n] = (bf16)(v > 0.f ? v : 0.f);
            }
        }
    }
}

// gemm3: out[perm] = H2@W2 + b2 (fp32 scatter). K=HD, NTY=2.
__global__ __launch_bounds__(256, 3) void k_gemm3(
    const bf16* __restrict__ Ain, const bf16* __restrict__ Bt, const float* __restrict__ bias,
    float* __restrict__ out, const int* __restrict__ perm,
    const int* __restrict__ tileE, const int* __restrict__ tileR,
    const int* __restrict__ off, const int* __restrict__ ntp)
{
    __shared__ bf16 As[BM * BK];
    __shared__ bf16 Bs[BN * BK];
    DECODE_TILE(2, BN)
    f32x4 acc[4][4] = {};
    const bf16* Ab = Ain + (size_t)(base + row0) * HD;
    const bf16* Bb = Bt  + ((size_t)e * OD + n0) * HD;
    GEMM_KLOOP(HD)
    for (int i = 0; i < 4; i++) {
        int rb = wm * 64 + i * 16 + qd * 4;
        for (int r = 0; r < 4; r++) {
            int m = rb + r;
            if (m >= valid) continue;
            int tok = perm[base + row0 + m];
            size_t orow = (size_t)tok * OD;
            for (int j = 0; j < 4; j++) {
                int n = n0 + wn * 64 + j * 16 + lr;
                out[orow + n] = acc[i][j][r] + bias[e * OD + n];
            }
        }
    }
}

// ---------------- launch ----------------
extern "C" void kernel_launch(void* const* d_in, const int* in_sizes, int n_in,
                              void* d_out, int out_size, void* d_ws, size_t ws_size,
                              hipStream_t stream) {
    const float* x   = (const float*)d_in[0];
    const int*   sel = (const int*)d_in[1];
    const float* Wg  = (const float*)d_in[2];
    const float* bg  = (const float*)d_in[3];
    const float* Wu  = (const float*)d_in[4];
    const float* bu  = (const float*)d_in[5];
    const float* W1  = (const float*)d_in[6];
    const float* b1  = (const float*)d_in[7];
    const float* W2  = (const float*)d_in[8];
    const float* b2  = (const float*)d_in[9];
    float* out = (float*)d_out;

    char* ws = (char*)d_ws;
    int* cnt   = (int*)(ws + O_CNT);
    int* cur   = (int*)(ws + O_CUR);
    int* off   = (int*)(ws + O_OFF);
    int* nt    = (int*)(ws + O_NT);
    int* tileE = (int*)(ws + O_TE);
    int* tileR = (int*)(ws + O_TR);
    int* perm  = (int*)(ws + O_PERM);
    bf16* Xp   = (bf16*)(ws + O_XP);
    bf16* Wgt  = (bf16*)(ws + O_WG);
    bf16* Wut  = (bf16*)(ws + O_WU);
    bf16* W1t  = (bf16*)(ws + O_W1);
    bf16* W2t  = (bf16*)(ws + O_W2);
    bf16* Hbuf = (bf16*)(ws + O_H);
    bf16* H2   = (bf16*)(ws + O_H2);

    hipMemsetAsync(ws, 0, 256, stream);

    k_hist   <<<NTOK / 256, 256, 0, stream>>>(sel, cnt);
    k_plan   <<<1, 64, 0, stream>>>(cnt, off, tileE, tileR, nt);
    k_scatter<<<NTOK / 256, 256, 0, stream>>>(sel, off, cur, perm);
    k_gather <<<NTOK * 64 / 256, 256, 0, stream>>>(x, perm, Xp);

    k_transpose_all<<<NEXP * TPE, 256, 0, stream>>>(Wg, Wgt, Wu, Wut, W1, W1t, W2, W2t);

    // 1D swizzled grids: RT8 * NTY * 8
    k_swiglu<<<RT8 * 16 * 8, 256, 0, stream>>>(Xp, Wgt, Wut, bg, bu, Hbuf,
                                               tileE, tileR, off, nt);
    k_gemm2 <<<RT8 * 8 * 8, 256, 0, stream>>>(Hbuf, W1t, b1, H2,
                                              tileE, tileR, off, nt);
    k_gemm3 <<<RT8 * 2 * 8, 256, 0, stream>>>(H2, W2t, b2, out, perm,
                                              tileE, tileR, off, nt);
}